// Round 9
// baseline (1786.356 us; speedup 1.0000x reference)
//
#include <hip/hip_runtime.h>

#define F 100
#define TS 256

typedef __attribute__((ext_vector_type(4))) unsigned short us4;
typedef __attribute__((ext_vector_type(8))) short short8;
typedef __attribute__((ext_vector_type(4))) float f32x4;

static __device__ __forceinline__ unsigned short f2bf(float f) {
    unsigned int u = __float_as_uint(f);
    unsigned int r = (u + 0x7FFF + ((u >> 16) & 1)) >> 16;
    return (unsigned short)r;
}
static __device__ __forceinline__ float bf2f(unsigned short u) {
    return __uint_as_float(((unsigned int)u) << 16);
}

// ---------------- CSR build over BOTH graphs ----------------
__global__ __launch_bounds__(TS)
void hist2_kernel(const int* __restrict__ dst0, const int* __restrict__ dst1,
                  int h, int E, int N,
                  int* __restrict__ cnt1, int* __restrict__ cnt2)
{
    for (int idx = blockIdx.x * TS + threadIdx.x; idx < 2 * E; idx += gridDim.x * TS) {
        int g = idx >= E;
        int e = idx - g * E;
        int d = (g ? dst1 : dst0)[e];
        atomicAdd((e < h ? cnt1 : cnt2) + g * N + d, 1);
    }
}

// 4 independent scans in one dispatch: block 0..3 = (half,g)
__global__ __launch_bounds__(1024)
void scan4_kernel(const int* __restrict__ cnt1, const int* __restrict__ cnt2,
                  int* __restrict__ rp1, int* __restrict__ rp2, int n)
{
    const int which = blockIdx.x;
    const int hf = which >> 1, g = which & 1;
    const int* cnt = (hf ? cnt2 : cnt1) + g * n;
    int* rp = (hf ? rp2 : rp1) + g * (n + 1);
    __shared__ int buf[1024];
    __shared__ int carry_s;
    const int t = threadIdx.x;
    if (t == 0) carry_s = 0;
    __syncthreads();
    for (int base = 0; base < n; base += 8192) {
        int v[8], s = 0;
        #pragma unroll
        for (int j = 0; j < 8; ++j) {
            int idx = base + t * 8 + j;
            int x = (idx < n) ? cnt[idx] : 0;
            v[j] = s; s += x;
        }
        buf[t] = s;
        __syncthreads();
        for (int off = 1; off < 1024; off <<= 1) {
            int y = (t >= off) ? buf[t - off] : 0;
            __syncthreads();
            buf[t] += y;
            __syncthreads();
        }
        int excl = carry_s + buf[t] - s;
        #pragma unroll
        for (int j = 0; j < 8; ++j) {
            int idx = base + t * 8 + j;
            if (idx < n) rp[idx] = excl + v[j];
        }
        __syncthreads();
        if (t == 1023) carry_s += buf[1023];
        __syncthreads();
    }
    if (t == 0) rp[n] = carry_s;
}

// scatter both graphs; es stored with +g*N (global node id)
__global__ __launch_bounds__(TS)
void scatter2_kernel(const int* __restrict__ src0, const int* __restrict__ dst0,
                     const int* __restrict__ src1, const int* __restrict__ dst1,
                     int h, int E, int N,
                     const int* __restrict__ rp1, const int* __restrict__ rp2,
                     int* __restrict__ cur1, int* __restrict__ cur2,
                     int* __restrict__ perm1, int* __restrict__ perm2,
                     int* __restrict__ es1, int* __restrict__ es2)
{
    for (int idx = blockIdx.x * TS + threadIdx.x; idx < 2 * E; idx += gridDim.x * TS) {
        int g = idx >= E;
        int e = idx - g * E;
        int d = (g ? dst1 : dst0)[e];
        int s = (g ? src1 : src0)[e];
        if (e < h) {
            int p = rp1[g * (N + 1) + d] + atomicAdd(&cur1[g * N + d], 1);
            perm1[g * h + p] = e; es1[g * h + p] = s + g * N;
        } else {
            int p = rp2[g * (N + 1) + d] + atomicAdd(&cur2[g * N + d], 1);
            perm2[g * h + p] = e; es2[g * h + p] = s + g * N;
        }
    }
}

// ---------------- pack conv W: 12 slices [112][128] bf16, transposed ----------------
__global__ __launch_bounds__(TS)
void pack_w_kernel(const float* w0, const float* w1, const float* w2, const float* w3,
                   unsigned short* __restrict__ Wp)
{
    int i = blockIdx.x * TS + threadIdx.x;
    if (i >= 12 * 112 * 128) return;
    int s = i / (112 * 128);
    int r = i - s * (112 * 128);
    int c = r >> 7, k = r & 127;
    int wi = s & 3, grp = s >> 2;
    const float* w = (wi == 0) ? w0 : (wi == 1) ? w1 : (wi == 2) ? w2 : w3;
    int off = (grp == 0) ? F : ((grp == 1) ? 0 : 2 * F);
    unsigned short v = 0;
    if (c < 100 && k < 100) v = f2bf(w[(off + k) * F + c]);
    Wp[i] = v;
}

__global__ __launch_bounds__(TS)
void pack_w2_kernel(const float* __restrict__ w, int K, int Nc, int ldb,
                    unsigned short* __restrict__ out)
{
    int i = blockIdx.x * TS + threadIdx.x;
    if (i >= 112 * 128) return;
    int c = i >> 7, k = i & 127;
    unsigned short v = 0;
    if (c < Nc && k < K) v = f2bf(w[k * ldb + c]);
    out[i] = v;
}

// ---------------- pack node features (both graphs) fp32 -> bf16, 128-pad ----------------
__global__ __launch_bounds__(TS)
void pack_x2_kernel(const float* __restrict__ x0, const float* __restrict__ x1,
                    int N, unsigned short* __restrict__ xb)
{
    const size_t total = (size_t)N * 2 * 32;
    for (size_t i = (size_t)blockIdx.x * TS + threadIdx.x; i < total; i += (size_t)gridDim.x * TS) {
        int n = (int)(i >> 5), q = (int)(i & 31);
        int g = n >= N;
        const float* x = g ? x1 : x0;
        int nl = n - g * N;
        us4 o = (us4){0, 0, 0, 0};
        if (q < 25) {
            float4 v = *(const float4*)&x[(size_t)nl * 100 + q * 4];
            o.x = f2bf(v.x); o.y = f2bf(v.y); o.z = f2bf(v.z); o.w = f2bf(v.w);
        }
        *(us4*)&xb[((size_t)n << 7) + q * 4] = o;
    }
}

// ---------------- MFMA node transforms; SWAPPED operands -> vectorized us4 stores ----------------
__global__ __launch_bounds__(TS)
void gemm_node_mfma(const unsigned short* __restrict__ xb,
                    const unsigned short* __restrict__ B0, const unsigned short* __restrict__ B1,
                    const unsigned short* __restrict__ B2, const unsigned short* __restrict__ B3,
                    unsigned short* __restrict__ NTb,
                    int M)
{
    const int t = threadIdx.x, lane = t & 63, wv = t >> 6;
    const int rA = lane & 15, kg = lane >> 4;
    const unsigned short* Bp[4] = {B0, B1, B2, B3};
    const int ntiles = (M + 15) >> 4;
    for (int tile = blockIdx.x * 4 + wv; tile < ntiles; tile += gridDim.x * 4) {
        const int base = tile << 4;
        const int arow = min(base + rA, M - 1);
        short8 A[4];
        #pragma unroll
        for (int ks = 0; ks < 4; ++ks)
            A[ks] = *(const short8*)&xb[((size_t)arow << 7) + ks * 32 + kg * 8];
        const int row = base + rA;
        #pragma unroll
        for (int sel = 0; sel < 4; ++sel) {
            const unsigned short* B = Bp[sel];
            f32x4 C[7];
            #pragma unroll
            for (int nf = 0; nf < 7; ++nf) C[nf] = (f32x4){0.f, 0.f, 0.f, 0.f};
            #pragma unroll
            for (int ks = 0; ks < 4; ++ks) {
                #pragma unroll
                for (int nf = 0; nf < 7; ++nf) {
                    short8 Bf = *(const short8*)&B[(size_t)(rA + nf * 16) * 128 + ks * 32 + kg * 8];
                    C[nf] = __builtin_amdgcn_mfma_f32_16x16x32_bf16(Bf, A[ks], C[nf], 0, 0, 0);
                }
            }
            if (row < M) {
                #pragma unroll
                for (int nf = 0; nf < 7; ++nf) {
                    const int cb = nf * 16 + kg * 4;
                    if (cb < 100) {
                        us4 o;
                        o.x = f2bf(C[nf][0]); o.y = f2bf(C[nf][1]);
                        o.z = f2bf(C[nf][2]); o.w = f2bf(C[nf][3]);
                        *(us4*)&NTb[(size_t)row * 400 + sel * 100 + cb] = o;
                    }
                }
            }
        }
    }
}

// ---------------- fused quad edge GEMM, LDS-staged gather, 512-thread wave-sel split ----------------
// 8 waves: waves 0-3 compute sel0, waves 4-7 compute sel1 from the SAME LDS tile.
// Per-wave regs: C 28 + A 16 + raw 16 (8 threads/row staging, 4 indep float4 each)
// -> <=128 VGPR -> 4 waves/SIMD. sched_barrier(0) after prefetch issue pins the
// gather loads EARLY (the R6 failure was the compiler sinking them past the MFMAs).
__global__ __launch_bounds__(512, 4)
void gemm_edge_quad(const float* __restrict__ ea0, const float* __restrict__ ea1,
                    const int* __restrict__ perm,     // [2h] edge ids (local to graph)
                    const unsigned short* __restrict__ W0,  // conv0 mid slice [112][128]
                    const unsigned short* __restrict__ W1,  // conv1 mid slice [112][128]
                    unsigned short* __restrict__ P0,        // [2h][100] CSR order
                    unsigned short* __restrict__ P1,        // [2h][100] CSR order
                    int h)
{
    __shared__ unsigned short sA[2][64][136];   // 2 x 17408 B
    const int t = threadIdx.x, lane = t & 63, wv = t >> 6;   // wv in [0,8)
    const int rA = lane & 15, kg = lane >> 4;
    const int lrow = (wv & 3) * 16 + rA;
    const unsigned short* W = (wv >> 2) ? W1 : W0;
    unsigned short* P = (wv >> 2) ? P1 : P0;
    const int M = 2 * h;                 // multiple of 64
    const int ngrp = M >> 6;
    const int r_loc = t >> 3, sub = t & 7;

    int grp = blockIdx.x;
    if (grp >= ngrp) return;

    // ---- prologue: stage group 'grp' into buf 0 ----
    {
        const int grow = (grp << 6) + r_loc;
        const int g = grow >= h;
        const int e = perm[grow];
        const float* ea = (g ? ea1 : ea0) + (size_t)e * 100;
        float4 raw[4];
        #pragma unroll
        for (int j = 0; j < 4; ++j) {
            const int q = sub + 8 * j;
            if (q < 25) raw[j] = *(const float4*)&ea[q * 4];
        }
        #pragma unroll
        for (int j = 0; j < 4; ++j) {
            const int q = sub + 8 * j;       // covers 0..31 exactly once across sub
            us4 o = (us4){0, 0, 0, 0};
            if (q < 25) {
                o.x = f2bf(raw[j].x); o.y = f2bf(raw[j].y);
                o.z = f2bf(raw[j].z); o.w = f2bf(raw[j].w);
            }
            *(us4*)&sA[0][r_loc][q * 4] = o;
        }
    }
    __syncthreads();

    int cur = 0;
    while (true) {
        const int nxt = grp + gridDim.x;
        const bool more = nxt < ngrp;

        // ---- issue next group's gather loads early (independent, all in flight) ----
        float4 raw[4];
        if (more) {
            const int grow = (nxt << 6) + r_loc;
            const int g = grow >= h;
            const int e = perm[grow];
            const float* ea = (g ? ea1 : ea0) + (size_t)e * 100;
            #pragma unroll
            for (int j = 0; j < 4; ++j) {
                const int q = sub + 8 * j;
                if (q < 25) raw[j] = *(const float4*)&ea[q * 4];
            }
        }
        __builtin_amdgcn_sched_barrier(0);   // pin: loads issued above cannot sink below

        // ---- compute current group from LDS (one sel per wave) ----
        {
            short8 A[4];
            #pragma unroll
            for (int ks = 0; ks < 4; ++ks)
                A[ks] = *(const short8*)&sA[cur][lrow][ks * 32 + kg * 8];

            f32x4 C[7];
            #pragma unroll
            for (int nf = 0; nf < 7; ++nf) C[nf] = (f32x4){0.f, 0.f, 0.f, 0.f};
            #pragma unroll
            for (int ks = 0; ks < 4; ++ks) {
                #pragma unroll
                for (int nf = 0; nf < 7; ++nf) {
                    short8 Bf = *(const short8*)&W[(size_t)(rA + nf * 16) * 128 + ks * 32 + kg * 8];
                    C[nf] = __builtin_amdgcn_mfma_f32_16x16x32_bf16(Bf, A[ks], C[nf], 0, 0, 0);
                }
            }
            const int row = (grp << 6) + lrow;
            #pragma unroll
            for (int nf = 0; nf < 7; ++nf) {
                const int cb = nf * 16 + kg * 4;
                if (cb < 100) {
                    us4 o;
                    o.x = f2bf(C[nf][0]); o.y = f2bf(C[nf][1]);
                    o.z = f2bf(C[nf][2]); o.w = f2bf(C[nf][3]);
                    *(us4*)&P[(size_t)row * 100 + cb] = o;
                }
            }
        }

        if (!more) break;

        // ---- convert + write staged data into the other buffer ----
        #pragma unroll
        for (int j = 0; j < 4; ++j) {
            const int q = sub + 8 * j;
            us4 o = (us4){0, 0, 0, 0};
            if (q < 25) {
                o.x = f2bf(raw[j].x); o.y = f2bf(raw[j].y);
                o.z = f2bf(raw[j].z); o.w = f2bf(raw[j].w);
            }
            *(us4*)&sA[cur ^ 1][r_loc][q * 4] = o;
        }
        __syncthreads();
        cur ^= 1; grp = nxt;
    }
}

// ---------------- fused segment reduce + pack_sum, MLP-optimized edge walk ----------------
// Joint loop over the common prefix of the half-1/half-2 edge lists: per iteration
// TWO independent es->NT chains + two P loads (x unroll 2 = 4 chains in flight).
// Both halves accumulate into the same sum. Tails handled separately.
// mode 0: x from fp32 x0/x1 (conv0).  mode 1: x from bf16 xbin (conv1, X1b).
__global__ __launch_bounds__(TS)
void seg_reduce_fused(const unsigned short* __restrict__ PA,     // [2h][100] CSR order, half1
                      const unsigned short* __restrict__ PB,     // [2h][100] CSR order, half2
                      const int* __restrict__ es1, const int* __restrict__ es2,
                      const int* __restrict__ rp1, const int* __restrict__ rp2,
                      const float* __restrict__ cb, const float* __restrict__ cb2,
                      const unsigned short* __restrict__ NTb,    // [2N][400]
                      const float* __restrict__ x0, const float* __restrict__ x1,
                      const unsigned short* __restrict__ xbin,
                      unsigned short* __restrict__ Ab,           // [2N][128]
                      int N, int h, int mode)
{
    const int gid = blockIdx.x * TS + threadIdx.x;
    const int n = gid >> 5, q = gid & 31;
    if (n >= 2 * N) return;
    const int c4 = q * 4;
    if (q >= 25) {   // pad columns 100..127
        *(us4*)&Ab[((size_t)n << 7) + c4] = (us4){0, 0, 0, 0};
        return;
    }
    const int g = n >= N;
    const int nl = n - g * N;

    // per-half hoisted constants: NT[dst] + bias
    float d1x, d1y, d1z, d1w, d2x, d2y, d2z, d2w;
    {
        const us4 vd1 = *(const us4*)&NTb[(size_t)n * 400 + 0 * 100 + c4];
        const float4 b1 = *(const float4*)&cb[c4];
        d1x = bf2f(vd1.x) + b1.x; d1y = bf2f(vd1.y) + b1.y;
        d1z = bf2f(vd1.z) + b1.z; d1w = bf2f(vd1.w) + b1.w;
        const us4 vd2 = *(const us4*)&NTb[(size_t)n * 400 + 3 * 100 + c4];
        const float4 b2 = *(const float4*)&cb2[c4];
        d2x = bf2f(vd2.x) + b2.x; d2y = bf2f(vd2.y) + b2.y;
        d2z = bf2f(vd2.z) + b2.z; d2w = bf2f(vd2.w) + b2.w;
    }
    const int* rpg1 = rp1 + g * (N + 1);
    const int* rpg2 = rp2 + g * (N + 1);
    int pos1 = max(rpg1[nl], 0) + g * h;
    const int end1 = min(rpg1[nl + 1], h) + g * h;
    int pos2 = max(rpg2[nl], 0) + g * h;
    const int end2 = min(rpg2[nl + 1], h) + g * h;

    float ax = 0.f, ay = 0.f, az = 0.f, aw = 0.f;

    // ---- joint loop: both halves in flight ----
    const int common = min(end1 - pos1, end2 - pos2);
    #pragma unroll 2
    for (int i = 0; i < common; ++i) {
        const int s1 = es1[pos1 + i];
        const int s2 = es2[pos2 + i];
        const us4 pv1 = *(const us4*)&PA[(size_t)(pos1 + i) * 100 + c4];
        const us4 pv2 = *(const us4*)&PB[(size_t)(pos2 + i) * 100 + c4];
        const us4 v1 = *(const us4*)&NTb[(size_t)s1 * 400 + 1 * 100 + c4];
        const us4 v2 = *(const us4*)&NTb[(size_t)s2 * 400 + 2 * 100 + c4];
        ax += fmaxf(bf2f(pv1.x) + bf2f(v1.x) + d1x, 0.f)
            + fmaxf(bf2f(pv2.x) + bf2f(v2.x) + d2x, 0.f);
        ay += fmaxf(bf2f(pv1.y) + bf2f(v1.y) + d1y, 0.f)
            + fmaxf(bf2f(pv2.y) + bf2f(v2.y) + d2y, 0.f);
        az += fmaxf(bf2f(pv1.z) + bf2f(v1.z) + d1z, 0.f)
            + fmaxf(bf2f(pv2.z) + bf2f(v2.z) + d2z, 0.f);
        aw += fmaxf(bf2f(pv1.w) + bf2f(v1.w) + d1w, 0.f)
            + fmaxf(bf2f(pv2.w) + bf2f(v2.w) + d2w, 0.f);
    }
    pos1 += common; pos2 += common;

    // ---- tails ----
    #pragma unroll 2
    for (; pos1 < end1; ++pos1) {
        const int s = es1[pos1];
        const us4 pv = *(const us4*)&PA[(size_t)pos1 * 100 + c4];
        const us4 vs = *(const us4*)&NTb[(size_t)s * 400 + 1 * 100 + c4];
        ax += fmaxf(bf2f(pv.x) + bf2f(vs.x) + d1x, 0.f);
        ay += fmaxf(bf2f(pv.y) + bf2f(vs.y) + d1y, 0.f);
        az += fmaxf(bf2f(pv.z) + bf2f(vs.z) + d1z, 0.f);
        aw += fmaxf(bf2f(pv.w) + bf2f(vs.w) + d1w, 0.f);
    }
    #pragma unroll 2
    for (; pos2 < end2; ++pos2) {
        const int s = es2[pos2];
        const us4 pv = *(const us4*)&PB[(size_t)pos2 * 100 + c4];
        const us4 vs = *(const us4*)&NTb[(size_t)s * 400 + 2 * 100 + c4];
        ax += fmaxf(bf2f(pv.x) + bf2f(vs.x) + d2x, 0.f);
        ay += fmaxf(bf2f(pv.y) + bf2f(vs.y) + d2y, 0.f);
        az += fmaxf(bf2f(pv.z) + bf2f(vs.z) + d2z, 0.f);
        aw += fmaxf(bf2f(pv.w) + bf2f(vs.w) + d2w, 0.f);
    }

    float4 xv;
    if (mode == 0) {
        const float* x = g ? x1 : x0;
        xv = *(const float4*)&x[(size_t)nl * 100 + c4];
    } else {
        const us4 v = *(const us4*)&xbin[((size_t)n << 7) + c4];
        xv.x = bf2f(v.x); xv.y = bf2f(v.y); xv.z = bf2f(v.z); xv.w = bf2f(v.w);
    }
    us4 o;
    o.x = f2bf(ax + xv.x); o.y = f2bf(ay + xv.y);
    o.z = f2bf(az + xv.z); o.w = f2bf(aw + xv.w);
    *(us4*)&Ab[((size_t)n << 7) + c4] = o;
}

// ---------------- MFMA MLP hop, bf16 out [M][128] (pads zeroed), fused bias + relu ----------------
__global__ __launch_bounds__(TS)
void gemm_mlp_bf16out(const unsigned short* __restrict__ Ab,
                      const unsigned short* __restrict__ Wp,
                      const float* __restrict__ bias,
                      unsigned short* __restrict__ out,
                      int M, int Nc)
{
    const int t = threadIdx.x, lane = t & 63, wv = t >> 6;
    const int rA = lane & 15, kg = lane >> 4;
    const int ntiles = (M + 15) >> 4;
    for (int tile = blockIdx.x * 4 + wv; tile < ntiles; tile += gridDim.x * 4) {
        const int base = tile << 4;
        const int arow = min(base + rA, M - 1);
        f32x4 C[7];
        #pragma unroll
        for (int nf = 0; nf < 7; ++nf) C[nf] = (f32x4){0.f, 0.f, 0.f, 0.f};
        #pragma unroll
        for (int ks = 0; ks < 4; ++ks) {
            short8 A = *(const short8*)&Ab[((size_t)arow << 7) + ks * 32 + kg * 8];
            #pragma unroll
            for (int nf = 0; nf < 7; ++nf) {
                short8 B = *(const short8*)&Wp[(size_t)(rA + nf * 16) * 128 + ks * 32 + kg * 8];
                C[nf] = __builtin_amdgcn_mfma_f32_16x16x32_bf16(B, A, C[nf], 0, 0, 0);
            }
        }
        const int row = base + rA;
        if (row < M) {
            #pragma unroll
            for (int nf = 0; nf < 7; ++nf) {
                const int cb = nf * 16 + kg * 4;
                us4 o = (us4){0, 0, 0, 0};
                if (cb < Nc) {   // Nc multiple of 4
                    float4 bv = *(const float4*)&bias[cb];
                    o.x = f2bf(fmaxf(C[nf][0] + bv.x, 0.f));
                    o.y = f2bf(fmaxf(C[nf][1] + bv.y, 0.f));
                    o.z = f2bf(fmaxf(C[nf][2] + bv.z, 0.f));
                    o.w = f2bf(fmaxf(C[nf][3] + bv.w, 0.f));
                }
                *(us4*)&out[((size_t)row << 7) + cb] = o;
            }
            *(us4*)&out[((size_t)row << 7) + 112 + kg * 4] = (us4){0, 0, 0, 0};
        }
    }
}

// ---------------- MFMA MLP final hop, fp32 out [M][64], bias, no relu ----------------
__global__ __launch_bounds__(TS)
void gemm_mlp_f32out(const unsigned short* __restrict__ Ab,
                     const unsigned short* __restrict__ Wp,
                     const float* __restrict__ bias,
                     float* __restrict__ out,
                     int M)
{
    const int t = threadIdx.x, lane = t & 63, wv = t >> 6;
    const int rA = lane & 15, kg = lane >> 4;
    const int ntiles = (M + 15) >> 4;
    for (int tile = blockIdx.x * 4 + wv; tile < ntiles; tile += gridDim.x * 4) {
        const int base = tile << 4;
        const int arow = min(base + rA, M - 1);
        f32x4 C[4];
        #pragma unroll
        for (int nf = 0; nf < 4; ++nf) C[nf] = (f32x4){0.f, 0.f, 0.f, 0.f};
        #pragma unroll
        for (int ks = 0; ks < 2; ++ks) {
            short8 A = *(const short8*)&Ab[((size_t)arow << 7) + ks * 32 + kg * 8];
            #pragma unroll
            for (int nf = 0; nf < 4; ++nf) {
                short8 B = *(const short8*)&Wp[(size_t)(rA + nf * 16) * 128 + ks * 32 + kg * 8];
                C[nf] = __builtin_amdgcn_mfma_f32_16x16x32_bf16(B, A, C[nf], 0, 0, 0);
            }
        }
        const int row = base + rA;
        if (row < M) {
            #pragma unroll
            for (int nf = 0; nf < 4; ++nf) {
                const int cb = nf * 16 + kg * 4;
                float4 bv = *(const float4*)&bias[cb];
                float4 o;
                o.x = C[nf][0] + bv.x; o.y = C[nf][1] + bv.y;
                o.z = C[nf][2] + bv.z; o.w = C[nf][3] + bv.w;
                *(float4*)&out[(size_t)row * 64 + cb] = o;
            }
        }
    }
}

// ---------------- column sum for both graphs: out[g*64+c] = sum_n F2[g][n][c] ----------------
__global__ __launch_bounds__(TS)
void colsum2_kernel(const float* __restrict__ Fm, int N, float* __restrict__ out)
{
    __shared__ float red[4][2][64];
    const int t = threadIdx.x;
    const int c = t & 63, rg = t >> 6;
    float s0 = 0.f, s1 = 0.f;
    const int M = 2 * N;
    for (int r = blockIdx.x * 4 + rg; r < M; r += gridDim.x * 4) {
        float v = Fm[(size_t)r * 64 + c];
        if (r < N) s0 += v; else s1 += v;
    }
    red[rg][0][c] = s0; red[rg][1][c] = s1;
    __syncthreads();
    if (rg == 0) {
        atomicAdd(&out[c],      red[0][0][c] + red[1][0][c] + red[2][0][c] + red[3][0][c]);
        atomicAdd(&out[64 + c], red[0][1][c] + red[1][1][c] + red[2][1][c] + red[3][1][c]);
    }
}

extern "C" void kernel_launch(void* const* d_in, const int* in_sizes, int n_in,
                              void* d_out, int out_size, void* d_ws, size_t ws_size,
                              hipStream_t stream)
{
    const int N = in_sizes[0] / F;   // 50000
    const int E = in_sizes[1] / 2;   // 800000
    const int h = E / 2;             // 400000
    const int N2 = 2 * N, h2 = 2 * h;

    // ---- workspace layout (~875 MB) ----
    unsigned short* NTb  = (unsigned short*)d_ws;                    // [2N][400]   80 MB
    unsigned short* P1A = NTb + (size_t)N2 * 400;                    // [2h][100]  160 MB
    unsigned short* P1B = P1A + (size_t)h2 * 100;                    // [2h][100]  160 MB
    unsigned short* P2A = P1B + (size_t)h2 * 100;                    // [2h][100]  160 MB
    unsigned short* P2B = P2A + (size_t)h2 * 100;                    // [2h][100]  160 MB
    unsigned short* xb  = P2B + (size_t)h2 * 100;                    // [2N][128]  25.6 MB
    unsigned short* X1b = xb + (size_t)N2 * 128;                     // [2N][128]
    unsigned short* Ab  = X1b + (size_t)N2 * 128;                    // [2N][128]
    unsigned short* Hb  = Ab + (size_t)N2 * 128;                     // [2N][128]
    float* F2  = (float*)(Hb + (size_t)N2 * 128);                    // [2N][64]   25.6 MB
    int* rp1   = (int*)(F2 + (size_t)N2 * 64);                       // [2][N+1]
    int* rp2   = rp1 + 2 * (N + 1);                                  // [2][N+1]
    int* cnt1  = rp2 + 2 * (N + 1);                                  // [2N]
    int* cnt2  = cnt1 + N2;                                          // [2N]
    int* perm1 = cnt2 + N2;                                          // [2h]
    int* perm2 = perm1 + h2;                                         // [2h]
    int* es1   = perm2 + h2;                                         // [2h]
    int* es2   = es1 + h2;                                           // [2h]
    unsigned short* Wp = (unsigned short*)(es2 + h2);                // [12][112][128]
    unsigned short* Wm = Wp + (size_t)12 * 112 * 128;                // [4][112][128]

    const float* x0g0 = (const float*)d_in[0];
    const int*   ei0  = (const int*)d_in[1];
    const float* ea0  = (const float*)d_in[2];
    const float* x0g1 = (const float*)d_in[3];
    const int*   ei1  = (const int*)d_in[4];
    const float* ea1  = (const float*)d_in[5];
    const float* c1w  = (const float*)d_in[6];
    const float* c1b  = (const float*)d_in[7];
    const float* c1w2 = (const float*)d_in[8];
    const float* c1b2 = (const float*)d_in[9];
    const float* m1w1 = (const float*)d_in[10];
    const float* m1b1 = (const float*)d_in[11];
    const float* m1w2 = (const float*)d_in[12];
    const float* m1b2 = (const float*)d_in[13];
    const float* c2w  = (const float*)d_in[14];
    const float* c2b  = (const float*)d_in[15];
    const float* c2w2 = (const float*)d_in[16];
    const float* c2b2 = (const float*)d_in[17];
    const float* m2w1 = (const float*)d_in[18];
    const float* m2b1 = (const float*)d_in[19];
    const float* m2w2 = (const float*)d_in[20];
    const float* m2b2 = (const float*)d_in[21];

    hipMemsetAsync(d_out, 0, (size_t)out_size * sizeof(float), stream);

    const dim3 blk(TS);
    const size_t SL = (size_t)112 * 128;
    pack_w_kernel<<<(12 * 112 * 128 + TS - 1) / TS, blk, 0, stream>>>(c1w, c1w2, c2w, c2w2, Wp);
    pack_w2_kernel<<<56, blk, 0, stream>>>(m1w1, 100, 100, 100, Wm + 0 * SL);
    pack_w2_kernel<<<56, blk, 0, stream>>>(m1w2, 100, 100, 100, Wm + 1 * SL);
    pack_w2_kernel<<<56, blk, 0, stream>>>(m2w1, 100,  64,  64, Wm + 2 * SL);
    pack_w2_kernel<<<56, blk, 0, stream>>>(m2w2,  64,  64,  64, Wm + 3 * SL);

    // ---- CSR build + packing, both graphs ----
    hipMemsetAsync(cnt1, 0, 2 * (size_t)N2 * sizeof(int), stream);
    hist2_kernel<<<2048, blk, 0, stream>>>(ei0 + E, ei1 + E, h, E, N, cnt1, cnt2);
    scan4_kernel<<<4, 1024, 0, stream>>>(cnt1, cnt2, rp1, rp2, N);
    hipMemsetAsync(cnt1, 0, 2 * (size_t)N2 * sizeof(int), stream);
    scatter2_kernel<<<2048, blk, 0, stream>>>(ei0, ei0 + E, ei1, ei1 + E, h, E, N,
                                              rp1, rp2, cnt1, cnt2, perm1, perm2, es1, es2);
    pack_x2_kernel<<<2048, blk, 0, stream>>>(x0g0, x0g1, N, xb);

    // ---- quad edge GEMMs: one gathered pass over ea produces P for BOTH convs ----
    gemm_edge_quad<<<2048, dim3(512), 0, stream>>>(ea0, ea1, perm1,
                                                   Wp + 0 * SL, Wp + 2 * SL, P1A, P2A, h);
    gemm_edge_quad<<<2048, dim3(512), 0, stream>>>(ea0, ea1, perm2,
                                                   Wp + 1 * SL, Wp + 3 * SL, P1B, P2B, h);

    const int nblkR = (N2 * 32 + TS - 1) / TS;
    for (int conv = 0; conv < 2; ++conv) {
        const float* cb  = conv ? c2b  : c1b;
        const float* cb2 = conv ? c2b2 : c1b2;
        const unsigned short* xin = conv ? X1b : xb;
        const int iw  = conv ? 2 : 0;
        const int iw2 = conv ? 3 : 1;
        const unsigned short* PA = conv ? P2A : P1A;
        const unsigned short* PB = conv ? P2B : P1B;

        // node transforms: sel0=lo(cw), sel1=hi(cw), sel2=lo(cw2), sel3=hi(cw2)
        gemm_node_mfma<<<2048, blk, 0, stream>>>(xin,
            Wp + (size_t)(4 + iw)  * SL, Wp + (size_t)(8 + iw)  * SL,
            Wp + (size_t)(4 + iw2) * SL, Wp + (size_t)(8 + iw2) * SL,
            NTb, N2);

        // fused reduction over both halves + pack_sum -> Ab (bf16) directly
        seg_reduce_fused<<<nblkR, blk, 0, stream>>>(PA, PB, es1, es2, rp1, rp2,
                                                    cb, cb2, NTb,
                                                    x0g0, x0g1, X1b, Ab,
                                                    N, h, conv);

        if (conv == 0) {
            // X1b = relu(mlp1(Ab))
            gemm_mlp_bf16out<<<2048, blk, 0, stream>>>(Ab, Wm + 0 * SL, m1b1, Hb,  N2, 100);
            gemm_mlp_bf16out<<<2048, blk, 0, stream>>>(Hb, Wm + 1 * SL, m1b2, X1b, N2, 100);
        } else {
            // F2 = mlp2(Ab)
            gemm_mlp_bf16out<<<2048, blk, 0, stream>>>(Ab, Wm + 2 * SL, m2b1, Hb, N2, 64);
            gemm_mlp_f32out<<<2048, blk, 0, stream>>>(Hb, Wm + 3 * SL, m2b2, F2, N2);
        }
    }
    colsum2_kernel<<<512, blk, 0, stream>>>(F2, N, (float*)d_out);
    (void)ws_size; (void)n_in;
}

// Round 10
// 1428.121 us; speedup vs baseline: 1.2508x; 1.2508x over previous
//
#include <hip/hip_runtime.h>

#define F 100
#define TS 256

typedef __attribute__((ext_vector_type(4))) unsigned short us4;
typedef __attribute__((ext_vector_type(8))) short short8;
typedef __attribute__((ext_vector_type(4))) float f32x4;

static __device__ __forceinline__ unsigned short f2bf(float f) {
    unsigned int u = __float_as_uint(f);
    unsigned int r = (u + 0x7FFF + ((u >> 16) & 1)) >> 16;
    return (unsigned short)r;
}
static __device__ __forceinline__ float bf2f(unsigned short u) {
    return __uint_as_float(((unsigned int)u) << 16);
}

// ---------------- CSR build over BOTH graphs ----------------
__global__ __launch_bounds__(TS)
void hist2_kernel(const int* __restrict__ dst0, const int* __restrict__ dst1,
                  int h, int E, int N,
                  int* __restrict__ cnt1, int* __restrict__ cnt2)
{
    for (int idx = blockIdx.x * TS + threadIdx.x; idx < 2 * E; idx += gridDim.x * TS) {
        int g = idx >= E;
        int e = idx - g * E;
        int d = (g ? dst1 : dst0)[e];
        atomicAdd((e < h ? cnt1 : cnt2) + g * N + d, 1);
    }
}

// 4 independent scans in one dispatch: block 0..3 = (half,g)
__global__ __launch_bounds__(1024)
void scan4_kernel(const int* __restrict__ cnt1, const int* __restrict__ cnt2,
                  int* __restrict__ rp1, int* __restrict__ rp2, int n)
{
    const int which = blockIdx.x;
    const int hf = which >> 1, g = which & 1;
    const int* cnt = (hf ? cnt2 : cnt1) + g * n;
    int* rp = (hf ? rp2 : rp1) + g * (n + 1);
    __shared__ int buf[1024];
    __shared__ int carry_s;
    const int t = threadIdx.x;
    if (t == 0) carry_s = 0;
    __syncthreads();
    for (int base = 0; base < n; base += 8192) {
        int v[8], s = 0;
        #pragma unroll
        for (int j = 0; j < 8; ++j) {
            int idx = base + t * 8 + j;
            int x = (idx < n) ? cnt[idx] : 0;
            v[j] = s; s += x;
        }
        buf[t] = s;
        __syncthreads();
        for (int off = 1; off < 1024; off <<= 1) {
            int y = (t >= off) ? buf[t - off] : 0;
            __syncthreads();
            buf[t] += y;
            __syncthreads();
        }
        int excl = carry_s + buf[t] - s;
        #pragma unroll
        for (int j = 0; j < 8; ++j) {
            int idx = base + t * 8 + j;
            if (idx < n) rp[idx] = excl + v[j];
        }
        __syncthreads();
        if (t == 1023) carry_s += buf[1023];
        __syncthreads();
    }
    if (t == 0) rp[n] = carry_s;
}

// scatter both graphs; es stored with +g*N (global node id)
__global__ __launch_bounds__(TS)
void scatter2_kernel(const int* __restrict__ src0, const int* __restrict__ dst0,
                     const int* __restrict__ src1, const int* __restrict__ dst1,
                     int h, int E, int N,
                     const int* __restrict__ rp1, const int* __restrict__ rp2,
                     int* __restrict__ cur1, int* __restrict__ cur2,
                     int* __restrict__ perm1, int* __restrict__ perm2,
                     int* __restrict__ es1, int* __restrict__ es2)
{
    for (int idx = blockIdx.x * TS + threadIdx.x; idx < 2 * E; idx += gridDim.x * TS) {
        int g = idx >= E;
        int e = idx - g * E;
        int d = (g ? dst1 : dst0)[e];
        int s = (g ? src1 : src0)[e];
        if (e < h) {
            int p = rp1[g * (N + 1) + d] + atomicAdd(&cur1[g * N + d], 1);
            perm1[g * h + p] = e; es1[g * h + p] = s + g * N;
        } else {
            int p = rp2[g * (N + 1) + d] + atomicAdd(&cur2[g * N + d], 1);
            perm2[g * h + p] = e; es2[g * h + p] = s + g * N;
        }
    }
}

// ---------------- pack conv W: 12 slices [112][128] bf16, transposed ----------------
__global__ __launch_bounds__(TS)
void pack_w_kernel(const float* w0, const float* w1, const float* w2, const float* w3,
                   unsigned short* __restrict__ Wp)
{
    int i = blockIdx.x * TS + threadIdx.x;
    if (i >= 12 * 112 * 128) return;
    int s = i / (112 * 128);
    int r = i - s * (112 * 128);
    int c = r >> 7, k = r & 127;
    int wi = s & 3, grp = s >> 2;
    const float* w = (wi == 0) ? w0 : (wi == 1) ? w1 : (wi == 2) ? w2 : w3;
    int off = (grp == 0) ? F : ((grp == 1) ? 0 : 2 * F);
    unsigned short v = 0;
    if (c < 100 && k < 100) v = f2bf(w[(off + k) * F + c]);
    Wp[i] = v;
}

__global__ __launch_bounds__(TS)
void pack_w2_kernel(const float* __restrict__ w, int K, int Nc, int ldb,
                    unsigned short* __restrict__ out)
{
    int i = blockIdx.x * TS + threadIdx.x;
    if (i >= 112 * 128) return;
    int c = i >> 7, k = i & 127;
    unsigned short v = 0;
    if (c < Nc && k < K) v = f2bf(w[k * ldb + c]);
    out[i] = v;
}

// ---------------- pack node features (both graphs) fp32 -> bf16, 128-pad ----------------
__global__ __launch_bounds__(TS)
void pack_x2_kernel(const float* __restrict__ x0, const float* __restrict__ x1,
                    int N, unsigned short* __restrict__ xb)
{
    const size_t total = (size_t)N * 2 * 32;
    for (size_t i = (size_t)blockIdx.x * TS + threadIdx.x; i < total; i += (size_t)gridDim.x * TS) {
        int n = (int)(i >> 5), q = (int)(i & 31);
        int g = n >= N;
        const float* x = g ? x1 : x0;
        int nl = n - g * N;
        us4 o = (us4){0, 0, 0, 0};
        if (q < 25) {
            float4 v = *(const float4*)&x[(size_t)nl * 100 + q * 4];
            o.x = f2bf(v.x); o.y = f2bf(v.y); o.z = f2bf(v.z); o.w = f2bf(v.w);
        }
        *(us4*)&xb[((size_t)n << 7) + q * 4] = o;
    }
}

// ---------------- MFMA node transforms; SWAPPED operands -> vectorized us4 stores ----------------
__global__ __launch_bounds__(TS)
void gemm_node_mfma(const unsigned short* __restrict__ xb,
                    const unsigned short* __restrict__ B0, const unsigned short* __restrict__ B1,
                    const unsigned short* __restrict__ B2, const unsigned short* __restrict__ B3,
                    unsigned short* __restrict__ NTb,
                    int M)
{
    const int t = threadIdx.x, lane = t & 63, wv = t >> 6;
    const int rA = lane & 15, kg = lane >> 4;
    const unsigned short* Bp[4] = {B0, B1, B2, B3};
    const int ntiles = (M + 15) >> 4;
    for (int tile = blockIdx.x * 4 + wv; tile < ntiles; tile += gridDim.x * 4) {
        const int base = tile << 4;
        const int arow = min(base + rA, M - 1);
        short8 A[4];
        #pragma unroll
        for (int ks = 0; ks < 4; ++ks)
            A[ks] = *(const short8*)&xb[((size_t)arow << 7) + ks * 32 + kg * 8];
        const int row = base + rA;
        #pragma unroll
        for (int sel = 0; sel < 4; ++sel) {
            const unsigned short* B = Bp[sel];
            f32x4 C[7];
            #pragma unroll
            for (int nf = 0; nf < 7; ++nf) C[nf] = (f32x4){0.f, 0.f, 0.f, 0.f};
            #pragma unroll
            for (int ks = 0; ks < 4; ++ks) {
                #pragma unroll
                for (int nf = 0; nf < 7; ++nf) {
                    short8 Bf = *(const short8*)&B[(size_t)(rA + nf * 16) * 128 + ks * 32 + kg * 8];
                    C[nf] = __builtin_amdgcn_mfma_f32_16x16x32_bf16(Bf, A[ks], C[nf], 0, 0, 0);
                }
            }
            if (row < M) {
                #pragma unroll
                for (int nf = 0; nf < 7; ++nf) {
                    const int cb = nf * 16 + kg * 4;
                    if (cb < 100) {
                        us4 o;
                        o.x = f2bf(C[nf][0]); o.y = f2bf(C[nf][1]);
                        o.z = f2bf(C[nf][2]); o.w = f2bf(C[nf][3]);
                        *(us4*)&NTb[(size_t)row * 400 + sel * 100 + cb] = o;
                    }
                }
            }
        }
    }
}

// ---------------- fused quad edge GEMM, LDS-staged gather (R4/R8-proven: dual accumulators) ----------------
// QUAD IS CLOSED (R3/R6/R9 all regressed): the 188-VGPR dual-C schedule pins the 7
// prefetch float4s early; pressure-reducing restructures let the compiler serialize
// the gather (R3/R6) and tight bounds + sched_barrier cause scratch spills (R9).
__global__ __launch_bounds__(TS)
void gemm_edge_quad(const float* __restrict__ ea0, const float* __restrict__ ea1,
                    const int* __restrict__ perm,     // [2h] edge ids (local to graph)
                    const unsigned short* __restrict__ W0,  // conv0 mid slice [112][128]
                    const unsigned short* __restrict__ W1,  // conv1 mid slice [112][128]
                    unsigned short* __restrict__ P0,        // [2h][100] CSR order
                    unsigned short* __restrict__ P1,        // [2h][100] CSR order
                    int h)
{
    __shared__ unsigned short sA[2][64][136];   // 2 x 17408 B
    const int t = threadIdx.x, lane = t & 63, wv = t >> 6;
    const int rA = lane & 15, kg = lane >> 4;
    const int M = 2 * h;                 // multiple of 64
    const int ngrp = M >> 6;
    const int r_loc = t >> 2, sub = t & 3;

    int grp = blockIdx.x;
    if (grp >= ngrp) return;

    // ---- prologue: stage group 'grp' into buf 0 ----
    {
        const int grow = (grp << 6) + r_loc;
        const int g = grow >= h;
        const int e = perm[grow];
        const float* ea = (g ? ea1 : ea0) + (size_t)e * 100;
        float4 raw[7];
        #pragma unroll
        for (int j = 0; j < 7; ++j) {
            const int q = sub + 4 * j;
            if (q < 25) raw[j] = *(const float4*)&ea[q * 4];
        }
        #pragma unroll
        for (int j = 0; j < 8; ++j) {
            const int q = sub + 4 * j;
            us4 o = (us4){0, 0, 0, 0};
            if (j < 7 && q < 25) {
                o.x = f2bf(raw[j].x); o.y = f2bf(raw[j].y);
                o.z = f2bf(raw[j].z); o.w = f2bf(raw[j].w);
            }
            if (q < 32) *(us4*)&sA[0][r_loc][q * 4] = o;
        }
    }
    __syncthreads();

    int cur = 0;
    while (true) {
        const int nxt = grp + gridDim.x;
        const bool more = nxt < ngrp;

        // ---- issue next group's gather loads early (independent, all in flight) ----
        float4 raw[7];
        if (more) {
            const int grow = (nxt << 6) + r_loc;
            const int g = grow >= h;
            const int e = perm[grow];
            const float* ea = (g ? ea1 : ea0) + (size_t)e * 100;
            #pragma unroll
            for (int j = 0; j < 7; ++j) {
                const int q = sub + 4 * j;
                if (q < 25) raw[j] = *(const float4*)&ea[q * 4];
            }
        }

        // ---- compute current group from LDS ----
        {
            const int lrow = wv * 16 + rA;
            short8 A[4];
            #pragma unroll
            for (int ks = 0; ks < 4; ++ks)
                A[ks] = *(const short8*)&sA[cur][lrow][ks * 32 + kg * 8];

            f32x4 C0[7], C1[7];
            #pragma unroll
            for (int nf = 0; nf < 7; ++nf) {
                C0[nf] = (f32x4){0.f, 0.f, 0.f, 0.f};
                C1[nf] = (f32x4){0.f, 0.f, 0.f, 0.f};
            }
            #pragma unroll
            for (int ks = 0; ks < 4; ++ks) {
                #pragma unroll
                for (int nf = 0; nf < 7; ++nf) {
                    short8 B0f = *(const short8*)&W0[(size_t)(rA + nf * 16) * 128 + ks * 32 + kg * 8];
                    C0[nf] = __builtin_amdgcn_mfma_f32_16x16x32_bf16(B0f, A[ks], C0[nf], 0, 0, 0);
                    short8 B1f = *(const short8*)&W1[(size_t)(rA + nf * 16) * 128 + ks * 32 + kg * 8];
                    C1[nf] = __builtin_amdgcn_mfma_f32_16x16x32_bf16(B1f, A[ks], C1[nf], 0, 0, 0);
                }
            }
            const int row = (grp << 6) + lrow;
            #pragma unroll
            for (int nf = 0; nf < 7; ++nf) {
                const int cb = nf * 16 + kg * 4;
                if (cb < 100) {
                    us4 o0, o1;
                    o0.x = f2bf(C0[nf][0]); o0.y = f2bf(C0[nf][1]);
                    o0.z = f2bf(C0[nf][2]); o0.w = f2bf(C0[nf][3]);
                    o1.x = f2bf(C1[nf][0]); o1.y = f2bf(C1[nf][1]);
                    o1.z = f2bf(C1[nf][2]); o1.w = f2bf(C1[nf][3]);
                    *(us4*)&P0[(size_t)row * 100 + cb] = o0;
                    *(us4*)&P1[(size_t)row * 100 + cb] = o1;
                }
            }
        }

        if (!more) break;

        // ---- convert + write staged data into the other buffer ----
        #pragma unroll
        for (int j = 0; j < 8; ++j) {
            const int q = sub + 4 * j;
            us4 o = (us4){0, 0, 0, 0};
            if (j < 7 && q < 25) {
                o.x = f2bf(raw[j].x); o.y = f2bf(raw[j].y);
                o.z = f2bf(raw[j].z); o.w = f2bf(raw[j].w);
            }
            if (q < 32) *(us4*)&sA[cur ^ 1][r_loc][q * 4] = o;
        }
        __syncthreads();
        cur ^= 1; grp = nxt;
    }
}

// ---------------- fused segment reduce + pack_sum, dense 25-thread/node mapping ----------------
// All lanes active in the edge walk (n = gid/25, q = gid%25); pad columns of Ab are
// zeroed ONCE by an upfront memset (seg writes only cols < 100).
// Joint loop over both halves: 2 independent es->NT chains per iter x unroll 4 = 8 in flight.
// mode 0: x from fp32 x0/x1 (conv0).  mode 1: x from bf16 xbin (conv1, X1b).
__global__ __launch_bounds__(TS)
void seg_reduce_fused(const unsigned short* __restrict__ PA,     // [2h][100] CSR order, half1
                      const unsigned short* __restrict__ PB,     // [2h][100] CSR order, half2
                      const int* __restrict__ es1, const int* __restrict__ es2,
                      const int* __restrict__ rp1, const int* __restrict__ rp2,
                      const float* __restrict__ cb, const float* __restrict__ cb2,
                      const unsigned short* __restrict__ NTb,    // [2N][400]
                      const float* __restrict__ x0, const float* __restrict__ x1,
                      const unsigned short* __restrict__ xbin,
                      unsigned short* __restrict__ Ab,           // [2N][128], pads pre-zeroed
                      int N, int h, int mode)
{
    const unsigned gid = blockIdx.x * TS + threadIdx.x;
    const unsigned total = (unsigned)(2 * N) * 25u;
    if (gid >= total) return;
    const int n = (int)(gid / 25u);
    const int q = (int)(gid - (unsigned)n * 25u);
    const int c4 = q * 4;
    const int g = n >= N;
    const int nl = n - g * N;

    // per-half hoisted constants: NT[dst] + bias
    float d1x, d1y, d1z, d1w, d2x, d2y, d2z, d2w;
    {
        const us4 vd1 = *(const us4*)&NTb[(size_t)n * 400 + 0 * 100 + c4];
        const float4 b1 = *(const float4*)&cb[c4];
        d1x = bf2f(vd1.x) + b1.x; d1y = bf2f(vd1.y) + b1.y;
        d1z = bf2f(vd1.z) + b1.z; d1w = bf2f(vd1.w) + b1.w;
        const us4 vd2 = *(const us4*)&NTb[(size_t)n * 400 + 3 * 100 + c4];
        const float4 b2 = *(const float4*)&cb2[c4];
        d2x = bf2f(vd2.x) + b2.x; d2y = bf2f(vd2.y) + b2.y;
        d2z = bf2f(vd2.z) + b2.z; d2w = bf2f(vd2.w) + b2.w;
    }
    const int* rpg1 = rp1 + g * (N + 1);
    const int* rpg2 = rp2 + g * (N + 1);
    int pos1 = max(rpg1[nl], 0) + g * h;
    const int end1 = min(rpg1[nl + 1], h) + g * h;
    int pos2 = max(rpg2[nl], 0) + g * h;
    const int end2 = min(rpg2[nl + 1], h) + g * h;

    float ax = 0.f, ay = 0.f, az = 0.f, aw = 0.f;

    // ---- joint loop: both halves in flight ----
    const int common = min(end1 - pos1, end2 - pos2);
    #pragma unroll 4
    for (int i = 0; i < common; ++i) {
        const int s1 = es1[pos1 + i];
        const int s2 = es2[pos2 + i];
        const us4 pv1 = *(const us4*)&PA[(size_t)(pos1 + i) * 100 + c4];
        const us4 pv2 = *(const us4*)&PB[(size_t)(pos2 + i) * 100 + c4];
        const us4 v1 = *(const us4*)&NTb[(size_t)s1 * 400 + 1 * 100 + c4];
        const us4 v2 = *(const us4*)&NTb[(size_t)s2 * 400 + 2 * 100 + c4];
        ax += fmaxf(bf2f(pv1.x) + bf2f(v1.x) + d1x, 0.f)
            + fmaxf(bf2f(pv2.x) + bf2f(v2.x) + d2x, 0.f);
        ay += fmaxf(bf2f(pv1.y) + bf2f(v1.y) + d1y, 0.f)
            + fmaxf(bf2f(pv2.y) + bf2f(v2.y) + d2y, 0.f);
        az += fmaxf(bf2f(pv1.z) + bf2f(v1.z) + d1z, 0.f)
            + fmaxf(bf2f(pv2.z) + bf2f(v2.z) + d2z, 0.f);
        aw += fmaxf(bf2f(pv1.w) + bf2f(v1.w) + d1w, 0.f)
            + fmaxf(bf2f(pv2.w) + bf2f(v2.w) + d2w, 0.f);
    }
    pos1 += common; pos2 += common;

    // ---- tails ----
    #pragma unroll 2
    for (; pos1 < end1; ++pos1) {
        const int s = es1[pos1];
        const us4 pv = *(const us4*)&PA[(size_t)pos1 * 100 + c4];
        const us4 vs = *(const us4*)&NTb[(size_t)s * 400 + 1 * 100 + c4];
        ax += fmaxf(bf2f(pv.x) + bf2f(vs.x) + d1x, 0.f);
        ay += fmaxf(bf2f(pv.y) + bf2f(vs.y) + d1y, 0.f);
        az += fmaxf(bf2f(pv.z) + bf2f(vs.z) + d1z, 0.f);
        aw += fmaxf(bf2f(pv.w) + bf2f(vs.w) + d1w, 0.f);
    }
    #pragma unroll 2
    for (; pos2 < end2; ++pos2) {
        const int s = es2[pos2];
        const us4 pv = *(const us4*)&PB[(size_t)pos2 * 100 + c4];
        const us4 vs = *(const us4*)&NTb[(size_t)s * 400 + 2 * 100 + c4];
        ax += fmaxf(bf2f(pv.x) + bf2f(vs.x) + d2x, 0.f);
        ay += fmaxf(bf2f(pv.y) + bf2f(vs.y) + d2y, 0.f);
        az += fmaxf(bf2f(pv.z) + bf2f(vs.z) + d2z, 0.f);
        aw += fmaxf(bf2f(pv.w) + bf2f(vs.w) + d2w, 0.f);
    }

    float4 xv;
    if (mode == 0) {
        const float* x = g ? x1 : x0;
        xv = *(const float4*)&x[(size_t)nl * 100 + c4];
    } else {
        const us4 v = *(const us4*)&xbin[((size_t)n << 7) + c4];
        xv.x = bf2f(v.x); xv.y = bf2f(v.y); xv.z = bf2f(v.z); xv.w = bf2f(v.w);
    }
    us4 o;
    o.x = f2bf(ax + xv.x); o.y = f2bf(ay + xv.y);
    o.z = f2bf(az + xv.z); o.w = f2bf(aw + xv.w);
    *(us4*)&Ab[((size_t)n << 7) + c4] = o;
}

// ---------------- MFMA MLP hop, bf16 out [M][128] (pads zeroed), fused bias + relu ----------------
__global__ __launch_bounds__(TS)
void gemm_mlp_bf16out(const unsigned short* __restrict__ Ab,
                      const unsigned short* __restrict__ Wp,
                      const float* __restrict__ bias,
                      unsigned short* __restrict__ out,
                      int M, int Nc)
{
    const int t = threadIdx.x, lane = t & 63, wv = t >> 6;
    const int rA = lane & 15, kg = lane >> 4;
    const int ntiles = (M + 15) >> 4;
    for (int tile = blockIdx.x * 4 + wv; tile < ntiles; tile += gridDim.x * 4) {
        const int base = tile << 4;
        const int arow = min(base + rA, M - 1);
        f32x4 C[7];
        #pragma unroll
        for (int nf = 0; nf < 7; ++nf) C[nf] = (f32x4){0.f, 0.f, 0.f, 0.f};
        #pragma unroll
        for (int ks = 0; ks < 4; ++ks) {
            short8 A = *(const short8*)&Ab[((size_t)arow << 7) + ks * 32 + kg * 8];
            #pragma unroll
            for (int nf = 0; nf < 7; ++nf) {
                short8 B = *(const short8*)&Wp[(size_t)(rA + nf * 16) * 128 + ks * 32 + kg * 8];
                C[nf] = __builtin_amdgcn_mfma_f32_16x16x32_bf16(B, A, C[nf], 0, 0, 0);
            }
        }
        const int row = base + rA;
        if (row < M) {
            #pragma unroll
            for (int nf = 0; nf < 7; ++nf) {
                const int cb = nf * 16 + kg * 4;
                us4 o = (us4){0, 0, 0, 0};
                if (cb < Nc) {   // Nc multiple of 4
                    float4 bv = *(const float4*)&bias[cb];
                    o.x = f2bf(fmaxf(C[nf][0] + bv.x, 0.f));
                    o.y = f2bf(fmaxf(C[nf][1] + bv.y, 0.f));
                    o.z = f2bf(fmaxf(C[nf][2] + bv.z, 0.f));
                    o.w = f2bf(fmaxf(C[nf][3] + bv.w, 0.f));
                }
                *(us4*)&out[((size_t)row << 7) + cb] = o;
            }
            *(us4*)&out[((size_t)row << 7) + 112 + kg * 4] = (us4){0, 0, 0, 0};
        }
    }
}

// ---------------- MFMA MLP final hop, fp32 out [M][64], bias, no relu ----------------
__global__ __launch_bounds__(TS)
void gemm_mlp_f32out(const unsigned short* __restrict__ Ab,
                     const unsigned short* __restrict__ Wp,
                     const float* __restrict__ bias,
                     float* __restrict__ out,
                     int M)
{
    const int t = threadIdx.x, lane = t & 63, wv = t >> 6;
    const int rA = lane & 15, kg = lane >> 4;
    const int ntiles = (M + 15) >> 4;
    for (int tile = blockIdx.x * 4 + wv; tile < ntiles; tile += gridDim.x * 4) {
        const int base = tile << 4;
        const int arow = min(base + rA, M - 1);
        f32x4 C[4];
        #pragma unroll
        for (int nf = 0; nf < 4; ++nf) C[nf] = (f32x4){0.f, 0.f, 0.f, 0.f};
        #pragma unroll
        for (int ks = 0; ks < 2; ++ks) {
            short8 A = *(const short8*)&Ab[((size_t)arow << 7) + ks * 32 + kg * 8];
            #pragma unroll
            for (int nf = 0; nf < 4; ++nf) {
                short8 B = *(const short8*)&Wp[(size_t)(rA + nf * 16) * 128 + ks * 32 + kg * 8];
                C[nf] = __builtin_amdgcn_mfma_f32_16x16x32_bf16(B, A, C[nf], 0, 0, 0);
            }
        }
        const int row = base + rA;
        if (row < M) {
            #pragma unroll
            for (int nf = 0; nf < 4; ++nf) {
                const int cb = nf * 16 + kg * 4;
                float4 bv = *(const float4*)&bias[cb];
                float4 o;
                o.x = C[nf][0] + bv.x; o.y = C[nf][1] + bv.y;
                o.z = C[nf][2] + bv.z; o.w = C[nf][3] + bv.w;
                *(float4*)&out[(size_t)row * 64 + cb] = o;
            }
        }
    }
}

// ---------------- column sum for both graphs: out[g*64+c] = sum_n F2[g][n][c] ----------------
__global__ __launch_bounds__(TS)
void colsum2_kernel(const float* __restrict__ Fm, int N, float* __restrict__ out)
{
    __shared__ float red[4][2][64];
    const int t = threadIdx.x;
    const int c = t & 63, rg = t >> 6;
    float s0 = 0.f, s1 = 0.f;
    const int M = 2 * N;
    for (int r = blockIdx.x * 4 + rg; r < M; r += gridDim.x * 4) {
        float v = Fm[(size_t)r * 64 + c];
        if (r < N) s0 += v; else s1 += v;
    }
    red[rg][0][c] = s0; red[rg][1][c] = s1;
    __syncthreads();
    if (rg == 0) {
        atomicAdd(&out[c],      red[0][0][c] + red[1][0][c] + red[2][0][c] + red[3][0][c]);
        atomicAdd(&out[64 + c], red[0][1][c] + red[1][1][c] + red[2][1][c] + red[3][1][c]);
    }
}

extern "C" void kernel_launch(void* const* d_in, const int* in_sizes, int n_in,
                              void* d_out, int out_size, void* d_ws, size_t ws_size,
                              hipStream_t stream)
{
    const int N = in_sizes[0] / F;   // 50000
    const int E = in_sizes[1] / 2;   // 800000
    const int h = E / 2;             // 400000
    const int N2 = 2 * N, h2 = 2 * h;

    // ---- workspace layout (~875 MB) ----
    unsigned short* NTb  = (unsigned short*)d_ws;                    // [2N][400]   80 MB
    unsigned short* P1A = NTb + (size_t)N2 * 400;                    // [2h][100]  160 MB
    unsigned short* P1B = P1A + (size_t)h2 * 100;                    // [2h][100]  160 MB
    unsigned short* P2A = P1B + (size_t)h2 * 100;                    // [2h][100]  160 MB
    unsigned short* P2B = P2A + (size_t)h2 * 100;                    // [2h][100]  160 MB
    unsigned short* xb  = P2B + (size_t)h2 * 100;                    // [2N][128]  25.6 MB
    unsigned short* X1b = xb + (size_t)N2 * 128;                     // [2N][128]
    unsigned short* Ab  = X1b + (size_t)N2 * 128;                    // [2N][128]
    unsigned short* Hb  = Ab + (size_t)N2 * 128;                     // [2N][128]
    float* F2  = (float*)(Hb + (size_t)N2 * 128);                    // [2N][64]   25.6 MB
    int* rp1   = (int*)(F2 + (size_t)N2 * 64);                       // [2][N+1]
    int* rp2   = rp1 + 2 * (N + 1);                                  // [2][N+1]
    int* cnt1  = rp2 + 2 * (N + 1);                                  // [2N]
    int* cnt2  = cnt1 + N2;                                          // [2N]
    int* perm1 = cnt2 + N2;                                          // [2h]
    int* perm2 = perm1 + h2;                                         // [2h]
    int* es1   = perm2 + h2;                                         // [2h]
    int* es2   = es1 + h2;                                           // [2h]
    unsigned short* Wp = (unsigned short*)(es2 + h2);                // [12][112][128]
    unsigned short* Wm = Wp + (size_t)12 * 112 * 128;                // [4][112][128]

    const float* x0g0 = (const float*)d_in[0];
    const int*   ei0  = (const int*)d_in[1];
    const float* ea0  = (const float*)d_in[2];
    const float* x0g1 = (const float*)d_in[3];
    const int*   ei1  = (const int*)d_in[4];
    const float* ea1  = (const float*)d_in[5];
    const float* c1w  = (const float*)d_in[6];
    const float* c1b  = (const float*)d_in[7];
    const float* c1w2 = (const float*)d_in[8];
    const float* c1b2 = (const float*)d_in[9];
    const float* m1w1 = (const float*)d_in[10];
    const float* m1b1 = (const float*)d_in[11];
    const float* m1w2 = (const float*)d_in[12];
    const float* m1b2 = (const float*)d_in[13];
    const float* c2w  = (const float*)d_in[14];
    const float* c2b  = (const float*)d_in[15];
    const float* c2w2 = (const float*)d_in[16];
    const float* c2b2 = (const float*)d_in[17];
    const float* m2w1 = (const float*)d_in[18];
    const float* m2b1 = (const float*)d_in[19];
    const float* m2w2 = (const float*)d_in[20];
    const float* m2b2 = (const float*)d_in[21];

    hipMemsetAsync(d_out, 0, (size_t)out_size * sizeof(float), stream);
    // zero Ab once: pads (cols 100..127) stay zero — seg writes only cols < 100
    hipMemsetAsync(Ab, 0, (size_t)N2 * 128 * sizeof(unsigned short), stream);

    const dim3 blk(TS);
    const size_t SL = (size_t)112 * 128;
    pack_w_kernel<<<(12 * 112 * 128 + TS - 1) / TS, blk, 0, stream>>>(c1w, c1w2, c2w, c2w2, Wp);
    pack_w2_kernel<<<56, blk, 0, stream>>>(m1w1, 100, 100, 100, Wm + 0 * SL);
    pack_w2_kernel<<<56, blk, 0, stream>>>(m1w2, 100, 100, 100, Wm + 1 * SL);
    pack_w2_kernel<<<56, blk, 0, stream>>>(m2w1, 100,  64,  64, Wm + 2 * SL);
    pack_w2_kernel<<<56, blk, 0, stream>>>(m2w2,  64,  64,  64, Wm + 3 * SL);

    // ---- CSR build + packing, both graphs ----
    hipMemsetAsync(cnt1, 0, 2 * (size_t)N2 * sizeof(int), stream);
    hist2_kernel<<<2048, blk, 0, stream>>>(ei0 + E, ei1 + E, h, E, N, cnt1, cnt2);
    scan4_kernel<<<4, 1024, 0, stream>>>(cnt1, cnt2, rp1, rp2, N);
    hipMemsetAsync(cnt1, 0, 2 * (size_t)N2 * sizeof(int), stream);
    scatter2_kernel<<<2048, blk, 0, stream>>>(ei0, ei0 + E, ei1, ei1 + E, h, E, N,
                                              rp1, rp2, cnt1, cnt2, perm1, perm2, es1, es2);
    pack_x2_kernel<<<2048, blk, 0, stream>>>(x0g0, x0g1, N, xb);

    // ---- quad edge GEMMs: one gathered pass over ea produces P for BOTH convs ----
    gemm_edge_quad<<<2048, blk, 0, stream>>>(ea0, ea1, perm1,
                                             Wp + 0 * SL, Wp + 2 * SL, P1A, P2A, h);
    gemm_edge_quad<<<2048, blk, 0, stream>>>(ea0, ea1, perm2,
                                             Wp + 1 * SL, Wp + 3 * SL, P1B, P2B, h);

    const int nblkR = (N2 * 25 + TS - 1) / TS;
    for (int conv = 0; conv < 2; ++conv) {
        const float* cb  = conv ? c2b  : c1b;
        const float* cb2 = conv ? c2b2 : c1b2;
        const unsigned short* xin = conv ? X1b : xb;
        const int iw  = conv ? 2 : 0;
        const int iw2 = conv ? 3 : 1;
        const unsigned short* PA = conv ? P2A : P1A;
        const unsigned short* PB = conv ? P2B : P1B;

        // node transforms: sel0=lo(cw), sel1=hi(cw), sel2=lo(cw2), sel3=hi(cw2)
        gemm_node_mfma<<<2048, blk, 0, stream>>>(xin,
            Wp + (size_t)(4 + iw)  * SL, Wp + (size_t)(8 + iw)  * SL,
            Wp + (size_t)(4 + iw2) * SL, Wp + (size_t)(8 + iw2) * SL,
            NTb, N2);

        // fused reduction over both halves + pack_sum -> Ab (bf16) directly
        seg_reduce_fused<<<nblkR, blk, 0, stream>>>(PA, PB, es1, es2, rp1, rp2,
                                                    cb, cb2, NTb,
                                                    x0g0, x0g1, X1b, Ab,
                                                    N, h, conv);

        if (conv == 0) {
            // X1b = relu(mlp1(Ab))
            gemm_mlp_bf16out<<<2048, blk, 0, stream>>>(Ab, Wm + 0 * SL, m1b1, Hb,  N2, 100);
            gemm_mlp_bf16out<<<2048, blk, 0, stream>>>(Hb, Wm + 1 * SL, m1b2, X1b, N2, 100);
        } else {
            // F2 = mlp2(Ab)
            gemm_mlp_bf16out<<<2048, blk, 0, stream>>>(Ab, Wm + 2 * SL, m2b1, Hb, N2, 64);
            gemm_mlp_f32out<<<2048, blk, 0, stream>>>(Hb, Wm + 3 * SL, m2b2, F2, N2);
        }
    }
    colsum2_kernel<<<512, blk, 0, stream>>>(F2, N, (float*)d_out);
    (void)ws_size; (void)n_in;
}

// Round 11
// 1377.035 us; speedup vs baseline: 1.2972x; 1.0371x over previous
//
#include <hip/hip_runtime.h>

#define F 100
#define TS 256

typedef __attribute__((ext_vector_type(4))) unsigned short us4;
typedef __attribute__((ext_vector_type(8))) short short8;
typedef __attribute__((ext_vector_type(4))) float f32x4;

static __device__ __forceinline__ unsigned short f2bf(float f) {
    unsigned int u = __float_as_uint(f);
    unsigned int r = (u + 0x7FFF + ((u >> 16) & 1)) >> 16;
    return (unsigned short)r;
}
static __device__ __forceinline__ float bf2f(unsigned short u) {
    return __uint_as_float(((unsigned int)u) << 16);
}

// ---------------- CSR build over BOTH graphs ----------------
__global__ __launch_bounds__(TS)
void hist2_kernel(const int* __restrict__ dst0, const int* __restrict__ dst1,
                  int h, int E, int N,
                  int* __restrict__ cnt1, int* __restrict__ cnt2)
{
    for (int idx = blockIdx.x * TS + threadIdx.x; idx < 2 * E; idx += gridDim.x * TS) {
        int g = idx >= E;
        int e = idx - g * E;
        int d = (g ? dst1 : dst0)[e];
        atomicAdd((e < h ? cnt1 : cnt2) + g * N + d, 1);
    }
}

// 4 independent scans in one dispatch: block 0..3 = (half,g)
__global__ __launch_bounds__(1024)
void scan4_kernel(const int* __restrict__ cnt1, const int* __restrict__ cnt2,
                  int* __restrict__ rp1, int* __restrict__ rp2, int n)
{
    const int which = blockIdx.x;
    const int hf = which >> 1, g = which & 1;
    const int* cnt = (hf ? cnt2 : cnt1) + g * n;
    int* rp = (hf ? rp2 : rp1) + g * (n + 1);
    __shared__ int buf[1024];
    __shared__ int carry_s;
    const int t = threadIdx.x;
    if (t == 0) carry_s = 0;
    __syncthreads();
    for (int base = 0; base < n; base += 8192) {
        int v[8], s = 0;
        #pragma unroll
        for (int j = 0; j < 8; ++j) {
            int idx = base + t * 8 + j;
            int x = (idx < n) ? cnt[idx] : 0;
            v[j] = s; s += x;
        }
        buf[t] = s;
        __syncthreads();
        for (int off = 1; off < 1024; off <<= 1) {
            int y = (t >= off) ? buf[t - off] : 0;
            __syncthreads();
            buf[t] += y;
            __syncthreads();
        }
        int excl = carry_s + buf[t] - s;
        #pragma unroll
        for (int j = 0; j < 8; ++j) {
            int idx = base + t * 8 + j;
            if (idx < n) rp[idx] = excl + v[j];
        }
        __syncthreads();
        if (t == 1023) carry_s += buf[1023];
        __syncthreads();
    }
    if (t == 0) rp[n] = carry_s;
}

// scatter both graphs; es stored with +g*N (global node id)
__global__ __launch_bounds__(TS)
void scatter2_kernel(const int* __restrict__ src0, const int* __restrict__ dst0,
                     const int* __restrict__ src1, const int* __restrict__ dst1,
                     int h, int E, int N,
                     const int* __restrict__ rp1, const int* __restrict__ rp2,
                     int* __restrict__ cur1, int* __restrict__ cur2,
                     int* __restrict__ perm1, int* __restrict__ perm2,
                     int* __restrict__ es1, int* __restrict__ es2)
{
    for (int idx = blockIdx.x * TS + threadIdx.x; idx < 2 * E; idx += gridDim.x * TS) {
        int g = idx >= E;
        int e = idx - g * E;
        int d = (g ? dst1 : dst0)[e];
        int s = (g ? src1 : src0)[e];
        if (e < h) {
            int p = rp1[g * (N + 1) + d] + atomicAdd(&cur1[g * N + d], 1);
            perm1[g * h + p] = e; es1[g * h + p] = s + g * N;
        } else {
            int p = rp2[g * (N + 1) + d] + atomicAdd(&cur2[g * N + d], 1);
            perm2[g * h + p] = e; es2[g * h + p] = s + g * N;
        }
    }
}

// ---------------- pack conv W: 12 slices [112][128] bf16, transposed ----------------
__global__ __launch_bounds__(TS)
void pack_w_kernel(const float* w0, const float* w1, const float* w2, const float* w3,
                   unsigned short* __restrict__ Wp)
{
    int i = blockIdx.x * TS + threadIdx.x;
    if (i >= 12 * 112 * 128) return;
    int s = i / (112 * 128);
    int r = i - s * (112 * 128);
    int c = r >> 7, k = r & 127;
    int wi = s & 3, grp = s >> 2;
    const float* w = (wi == 0) ? w0 : (wi == 1) ? w1 : (wi == 2) ? w2 : w3;
    int off = (grp == 0) ? F : ((grp == 1) ? 0 : 2 * F);
    unsigned short v = 0;
    if (c < 100 && k < 100) v = f2bf(w[(off + k) * F + c]);
    Wp[i] = v;
}

__global__ __launch_bounds__(TS)
void pack_w2_kernel(const float* __restrict__ w, int K, int Nc, int ldb,
                    unsigned short* __restrict__ out)
{
    int i = blockIdx.x * TS + threadIdx.x;
    if (i >= 112 * 128) return;
    int c = i >> 7, k = i & 127;
    unsigned short v = 0;
    if (c < Nc && k < K) v = f2bf(w[k * ldb + c]);
    out[i] = v;
}

// ---------------- pack node features (both graphs) fp32 -> bf16, 128-pad ----------------
__global__ __launch_bounds__(TS)
void pack_x2_kernel(const float* __restrict__ x0, const float* __restrict__ x1,
                    int N, unsigned short* __restrict__ xb)
{
    const size_t total = (size_t)N * 2 * 32;
    for (size_t i = (size_t)blockIdx.x * TS + threadIdx.x; i < total; i += (size_t)gridDim.x * TS) {
        int n = (int)(i >> 5), q = (int)(i & 31);
        int g = n >= N;
        const float* x = g ? x1 : x0;
        int nl = n - g * N;
        us4 o = (us4){0, 0, 0, 0};
        if (q < 25) {
            float4 v = *(const float4*)&x[(size_t)nl * 100 + q * 4];
            o.x = f2bf(v.x); o.y = f2bf(v.y); o.z = f2bf(v.z); o.w = f2bf(v.w);
        }
        *(us4*)&xb[((size_t)n << 7) + q * 4] = o;
    }
}

// ---------------- MFMA node transforms; SWAPPED operands -> vectorized us4 stores ----------------
__global__ __launch_bounds__(TS)
void gemm_node_mfma(const unsigned short* __restrict__ xb,
                    const unsigned short* __restrict__ B0, const unsigned short* __restrict__ B1,
                    const unsigned short* __restrict__ B2, const unsigned short* __restrict__ B3,
                    unsigned short* __restrict__ NTb,
                    int M)
{
    const int t = threadIdx.x, lane = t & 63, wv = t >> 6;
    const int rA = lane & 15, kg = lane >> 4;
    const unsigned short* Bp[4] = {B0, B1, B2, B3};
    const int ntiles = (M + 15) >> 4;
    for (int tile = blockIdx.x * 4 + wv; tile < ntiles; tile += gridDim.x * 4) {
        const int base = tile << 4;
        const int arow = min(base + rA, M - 1);
        short8 A[4];
        #pragma unroll
        for (int ks = 0; ks < 4; ++ks)
            A[ks] = *(const short8*)&xb[((size_t)arow << 7) + ks * 32 + kg * 8];
        const int row = base + rA;
        #pragma unroll
        for (int sel = 0; sel < 4; ++sel) {
            const unsigned short* B = Bp[sel];
            f32x4 C[7];
            #pragma unroll
            for (int nf = 0; nf < 7; ++nf) C[nf] = (f32x4){0.f, 0.f, 0.f, 0.f};
            #pragma unroll
            for (int ks = 0; ks < 4; ++ks) {
                #pragma unroll
                for (int nf = 0; nf < 7; ++nf) {
                    short8 Bf = *(const short8*)&B[(size_t)(rA + nf * 16) * 128 + ks * 32 + kg * 8];
                    C[nf] = __builtin_amdgcn_mfma_f32_16x16x32_bf16(Bf, A[ks], C[nf], 0, 0, 0);
                }
            }
            if (row < M) {
                #pragma unroll
                for (int nf = 0; nf < 7; ++nf) {
                    const int cb = nf * 16 + kg * 4;
                    if (cb < 100) {
                        us4 o;
                        o.x = f2bf(C[nf][0]); o.y = f2bf(C[nf][1]);
                        o.z = f2bf(C[nf][2]); o.w = f2bf(C[nf][3]);
                        *(us4*)&NTb[(size_t)row * 400 + sel * 100 + cb] = o;
                    }
                }
            }
        }
    }
}

// ---------------- fused quad edge GEMM, BOTH halves in one dispatch ----------------
// QUAD SCHEDULE IS CLOSED (R3/R6/R9 all regressed): the 188-VGPR dual-C body pins the
// 7 prefetch float4s early; pressure-reducing restructures serialize the gather (R3/R6),
// tight bounds + sched_barrier spill (R9). Inner body is byte-identical to R4/R8.
// Merge: blocks [0,HG) process half A (perm1, W slices 0/2 -> P1A/P2A), blocks [HG,2HG)
// half B (perm2, slices 1/3 -> P1B/P2B). Block-uniform selection in the preamble only;
// removes the inter-dispatch drain (half-B blocks fill CUs while half-A tails finish).
__global__ __launch_bounds__(TS)
void gemm_edge_quad(const float* __restrict__ ea0, const float* __restrict__ ea1,
                    const int* __restrict__ perm1, const int* __restrict__ perm2,
                    const unsigned short* __restrict__ Wp,   // 12 slices of [112][128]
                    unsigned short* __restrict__ P1A, unsigned short* __restrict__ P2A,
                    unsigned short* __restrict__ P1B, unsigned short* __restrict__ P2B,
                    int h, int HG)
{
    __shared__ unsigned short sA[2][64][136];   // 2 x 17408 B
    const int t = threadIdx.x, lane = t & 63, wv = t >> 6;
    const int rA = lane & 15, kg = lane >> 4;
    const int M = 2 * h;                 // multiple of 64
    const int ngrp = M >> 6;
    const int r_loc = t >> 2, sub = t & 3;

    const int half = blockIdx.x >= HG;
    const int bid = blockIdx.x - (half ? HG : 0);
    const int* perm = half ? perm2 : perm1;
    const unsigned short* W0 = Wp + (size_t)(half ? 1 : 0) * (112 * 128);
    const unsigned short* W1 = Wp + (size_t)(half ? 3 : 2) * (112 * 128);
    unsigned short* P0 = half ? P1B : P1A;
    unsigned short* P1 = half ? P2B : P2A;

    int grp = bid;
    if (grp >= ngrp) return;

    // ---- prologue: stage group 'grp' into buf 0 ----
    {
        const int grow = (grp << 6) + r_loc;
        const int g = grow >= h;
        const int e = perm[grow];
        const float* ea = (g ? ea1 : ea0) + (size_t)e * 100;
        float4 raw[7];
        #pragma unroll
        for (int j = 0; j < 7; ++j) {
            const int q = sub + 4 * j;
            if (q < 25) raw[j] = *(const float4*)&ea[q * 4];
        }
        #pragma unroll
        for (int j = 0; j < 8; ++j) {
            const int q = sub + 4 * j;
            us4 o = (us4){0, 0, 0, 0};
            if (j < 7 && q < 25) {
                o.x = f2bf(raw[j].x); o.y = f2bf(raw[j].y);
                o.z = f2bf(raw[j].z); o.w = f2bf(raw[j].w);
            }
            if (q < 32) *(us4*)&sA[0][r_loc][q * 4] = o;
        }
    }
    __syncthreads();

    int cur = 0;
    while (true) {
        const int nxt = grp + HG;
        const bool more = nxt < ngrp;

        // ---- issue next group's gather loads early (independent, all in flight) ----
        float4 raw[7];
        if (more) {
            const int grow = (nxt << 6) + r_loc;
            const int g = grow >= h;
            const int e = perm[grow];
            const float* ea = (g ? ea1 : ea0) + (size_t)e * 100;
            #pragma unroll
            for (int j = 0; j < 7; ++j) {
                const int q = sub + 4 * j;
                if (q < 25) raw[j] = *(const float4*)&ea[q * 4];
            }
        }

        // ---- compute current group from LDS ----
        {
            const int lrow = wv * 16 + rA;
            short8 A[4];
            #pragma unroll
            for (int ks = 0; ks < 4; ++ks)
                A[ks] = *(const short8*)&sA[cur][lrow][ks * 32 + kg * 8];

            f32x4 C0[7], C1[7];
            #pragma unroll
            for (int nf = 0; nf < 7; ++nf) {
                C0[nf] = (f32x4){0.f, 0.f, 0.f, 0.f};
                C1[nf] = (f32x4){0.f, 0.f, 0.f, 0.f};
            }
            #pragma unroll
            for (int ks = 0; ks < 4; ++ks) {
                #pragma unroll
                for (int nf = 0; nf < 7; ++nf) {
                    short8 B0f = *(const short8*)&W0[(size_t)(rA + nf * 16) * 128 + ks * 32 + kg * 8];
                    C0[nf] = __builtin_amdgcn_mfma_f32_16x16x32_bf16(B0f, A[ks], C0[nf], 0, 0, 0);
                    short8 B1f = *(const short8*)&W1[(size_t)(rA + nf * 16) * 128 + ks * 32 + kg * 8];
                    C1[nf] = __builtin_amdgcn_mfma_f32_16x16x32_bf16(B1f, A[ks], C1[nf], 0, 0, 0);
                }
            }
            const int row = (grp << 6) + lrow;
            #pragma unroll
            for (int nf = 0; nf < 7; ++nf) {
                const int cb = nf * 16 + kg * 4;
                if (cb < 100) {
                    us4 o0, o1;
                    o0.x = f2bf(C0[nf][0]); o0.y = f2bf(C0[nf][1]);
                    o0.z = f2bf(C0[nf][2]); o0.w = f2bf(C0[nf][3]);
                    o1.x = f2bf(C1[nf][0]); o1.y = f2bf(C1[nf][1]);
                    o1.z = f2bf(C1[nf][2]); o1.w = f2bf(C1[nf][3]);
                    *(us4*)&P0[(size_t)row * 100 + cb] = o0;
                    *(us4*)&P1[(size_t)row * 100 + cb] = o1;
                }
            }
        }

        if (!more) break;

        // ---- convert + write staged data into the other buffer ----
        #pragma unroll
        for (int j = 0; j < 8; ++j) {
            const int q = sub + 4 * j;
            us4 o = (us4){0, 0, 0, 0};
            if (j < 7 && q < 25) {
                o.x = f2bf(raw[j].x); o.y = f2bf(raw[j].y);
                o.z = f2bf(raw[j].z); o.w = f2bf(raw[j].w);
            }
            if (q < 32) *(us4*)&sA[cur ^ 1][r_loc][q * 4] = o;
        }
        __syncthreads();
        cur ^= 1; grp = nxt;
    }
}

// ---------------- fused segment reduce + pack_sum (R8-proven), MLP-optimized edge walk ----------------
// Joint loop over the common prefix of the half-1/half-2 edge lists: per iteration
// TWO independent es->NT chains + two P loads (x unroll 2 = 4 chains in flight).
// mode 0: x from fp32 x0/x1 (conv0).  mode 1: x from bf16 xbin (conv1, X1b).
__global__ __launch_bounds__(TS)
void seg_reduce_fused(const unsigned short* __restrict__ PA,     // [2h][100] CSR order, half1
                      const unsigned short* __restrict__ PB,     // [2h][100] CSR order, half2
                      const int* __restrict__ es1, const int* __restrict__ es2,
                      const int* __restrict__ rp1, const int* __restrict__ rp2,
                      const float* __restrict__ cb, const float* __restrict__ cb2,
                      const unsigned short* __restrict__ NTb,    // [2N][400]
                      const float* __restrict__ x0, const float* __restrict__ x1,
                      const unsigned short* __restrict__ xbin,
                      unsigned short* __restrict__ Ab,           // [2N][128]
                      int N, int h, int mode)
{
    const int gid = blockIdx.x * TS + threadIdx.x;
    const int n = gid >> 5, q = gid & 31;
    if (n >= 2 * N) return;
    const int c4 = q * 4;
    if (q >= 25) {   // pad columns 100..127
        *(us4*)&Ab[((size_t)n << 7) + c4] = (us4){0, 0, 0, 0};
        return;
    }
    const int g = n >= N;
    const int nl = n - g * N;

    // per-half hoisted constants: NT[dst] + bias
    float d1x, d1y, d1z, d1w, d2x, d2y, d2z, d2w;
    {
        const us4 vd1 = *(const us4*)&NTb[(size_t)n * 400 + 0 * 100 + c4];
        const float4 b1 = *(const float4*)&cb[c4];
        d1x = bf2f(vd1.x) + b1.x; d1y = bf2f(vd1.y) + b1.y;
        d1z = bf2f(vd1.z) + b1.z; d1w = bf2f(vd1.w) + b1.w;
        const us4 vd2 = *(const us4*)&NTb[(size_t)n * 400 + 3 * 100 + c4];
        const float4 b2 = *(const float4*)&cb2[c4];
        d2x = bf2f(vd2.x) + b2.x; d2y = bf2f(vd2.y) + b2.y;
        d2z = bf2f(vd2.z) + b2.z; d2w = bf2f(vd2.w) + b2.w;
    }
    const int* rpg1 = rp1 + g * (N + 1);
    const int* rpg2 = rp2 + g * (N + 1);
    int pos1 = max(rpg1[nl], 0) + g * h;
    const int end1 = min(rpg1[nl + 1], h) + g * h;
    int pos2 = max(rpg2[nl], 0) + g * h;
    const int end2 = min(rpg2[nl + 1], h) + g * h;

    float ax = 0.f, ay = 0.f, az = 0.f, aw = 0.f;

    // ---- joint loop: both halves in flight ----
    const int common = min(end1 - pos1, end2 - pos2);
    #pragma unroll 2
    for (int i = 0; i < common; ++i) {
        const int s1 = es1[pos1 + i];
        const int s2 = es2[pos2 + i];
        const us4 pv1 = *(const us4*)&PA[(size_t)(pos1 + i) * 100 + c4];
        const us4 pv2 = *(const us4*)&PB[(size_t)(pos2 + i) * 100 + c4];
        const us4 v1 = *(const us4*)&NTb[(size_t)s1 * 400 + 1 * 100 + c4];
        const us4 v2 = *(const us4*)&NTb[(size_t)s2 * 400 + 2 * 100 + c4];
        ax += fmaxf(bf2f(pv1.x) + bf2f(v1.x) + d1x, 0.f)
            + fmaxf(bf2f(pv2.x) + bf2f(v2.x) + d2x, 0.f);
        ay += fmaxf(bf2f(pv1.y) + bf2f(v1.y) + d1y, 0.f)
            + fmaxf(bf2f(pv2.y) + bf2f(v2.y) + d2y, 0.f);
        az += fmaxf(bf2f(pv1.z) + bf2f(v1.z) + d1z, 0.f)
            + fmaxf(bf2f(pv2.z) + bf2f(v2.z) + d2z, 0.f);
        aw += fmaxf(bf2f(pv1.w) + bf2f(v1.w) + d1w, 0.f)
            + fmaxf(bf2f(pv2.w) + bf2f(v2.w) + d2w, 0.f);
    }
    pos1 += common; pos2 += common;

    // ---- tails ----
    #pragma unroll 2
    for (; pos1 < end1; ++pos1) {
        const int s = es1[pos1];
        const us4 pv = *(const us4*)&PA[(size_t)pos1 * 100 + c4];
        const us4 vs = *(const us4*)&NTb[(size_t)s * 400 + 1 * 100 + c4];
        ax += fmaxf(bf2f(pv.x) + bf2f(vs.x) + d1x, 0.f);
        ay += fmaxf(bf2f(pv.y) + bf2f(vs.y) + d1y, 0.f);
        az += fmaxf(bf2f(pv.z) + bf2f(vs.z) + d1z, 0.f);
        aw += fmaxf(bf2f(pv.w) + bf2f(vs.w) + d1w, 0.f);
    }
    #pragma unroll 2
    for (; pos2 < end2; ++pos2) {
        const int s = es2[pos2];
        const us4 pv = *(const us4*)&PB[(size_t)pos2 * 100 + c4];
        const us4 vs = *(const us4*)&NTb[(size_t)s * 400 + 2 * 100 + c4];
        ax += fmaxf(bf2f(pv.x) + bf2f(vs.x) + d2x, 0.f);
        ay += fmaxf(bf2f(pv.y) + bf2f(vs.y) + d2y, 0.f);
        az += fmaxf(bf2f(pv.z) + bf2f(vs.z) + d2z, 0.f);
        aw += fmaxf(bf2f(pv.w) + bf2f(vs.w) + d2w, 0.f);
    }

    float4 xv;
    if (mode == 0) {
        const float* x = g ? x1 : x0;
        xv = *(const float4*)&x[(size_t)nl * 100 + c4];
    } else {
        const us4 v = *(const us4*)&xbin[((size_t)n << 7) + c4];
        xv.x = bf2f(v.x); xv.y = bf2f(v.y); xv.z = bf2f(v.z); xv.w = bf2f(v.w);
    }
    us4 o;
    o.x = f2bf(ax + xv.x); o.y = f2bf(ay + xv.y);
    o.z = f2bf(az + xv.z); o.w = f2bf(aw + xv.w);
    *(us4*)&Ab[((size_t)n << 7) + c4] = o;
}

// ---------------- MFMA MLP hop, bf16 out [M][128] (pads zeroed), fused bias + relu ----------------
__global__ __launch_bounds__(TS)
void gemm_mlp_bf16out(const unsigned short* __restrict__ Ab,
                      const unsigned short* __restrict__ Wp,
                      const float* __restrict__ bias,
                      unsigned short* __restrict__ out,
                      int M, int Nc)
{
    const int t = threadIdx.x, lane = t & 63, wv = t >> 6;
    const int rA = lane & 15, kg = lane >> 4;
    const int ntiles = (M + 15) >> 4;
    for (int tile = blockIdx.x * 4 + wv; tile < ntiles; tile += gridDim.x * 4) {
        const int base = tile << 4;
        const int arow = min(base + rA, M - 1);
        f32x4 C[7];
        #pragma unroll
        for (int nf = 0; nf < 7; ++nf) C[nf] = (f32x4){0.f, 0.f, 0.f, 0.f};
        #pragma unroll
        for (int ks = 0; ks < 4; ++ks) {
            short8 A = *(const short8*)&Ab[((size_t)arow << 7) + ks * 32 + kg * 8];
            #pragma unroll
            for (int nf = 0; nf < 7; ++nf) {
                short8 B = *(const short8*)&Wp[(size_t)(rA + nf * 16) * 128 + ks * 32 + kg * 8];
                C[nf] = __builtin_amdgcn_mfma_f32_16x16x32_bf16(B, A, C[nf], 0, 0, 0);
            }
        }
        const int row = base + rA;
        if (row < M) {
            #pragma unroll
            for (int nf = 0; nf < 7; ++nf) {
                const int cb = nf * 16 + kg * 4;
                us4 o = (us4){0, 0, 0, 0};
                if (cb < Nc) {   // Nc multiple of 4
                    float4 bv = *(const float4*)&bias[cb];
                    o.x = f2bf(fmaxf(C[nf][0] + bv.x, 0.f));
                    o.y = f2bf(fmaxf(C[nf][1] + bv.y, 0.f));
                    o.z = f2bf(fmaxf(C[nf][2] + bv.z, 0.f));
                    o.w = f2bf(fmaxf(C[nf][3] + bv.w, 0.f));
                }
                *(us4*)&out[((size_t)row << 7) + cb] = o;
            }
            *(us4*)&out[((size_t)row << 7) + 112 + kg * 4] = (us4){0, 0, 0, 0};
        }
    }
}

// ---------------- MFMA MLP final hop, fp32 out [M][64], bias, no relu ----------------
__global__ __launch_bounds__(TS)
void gemm_mlp_f32out(const unsigned short* __restrict__ Ab,
                     const unsigned short* __restrict__ Wp,
                     const float* __restrict__ bias,
                     float* __restrict__ out,
                     int M)
{
    const int t = threadIdx.x, lane = t & 63, wv = t >> 6;
    const int rA = lane & 15, kg = lane >> 4;
    const int ntiles = (M + 15) >> 4;
    for (int tile = blockIdx.x * 4 + wv; tile < ntiles; tile += gridDim.x * 4) {
        const int base = tile << 4;
        const int arow = min(base + rA, M - 1);
        f32x4 C[4];
        #pragma unroll
        for (int nf = 0; nf < 4; ++nf) C[nf] = (f32x4){0.f, 0.f, 0.f, 0.f};
        #pragma unroll
        for (int ks = 0; ks < 2; ++ks) {
            short8 A = *(const short8*)&Ab[((size_t)arow << 7) + ks * 32 + kg * 8];
            #pragma unroll
            for (int nf = 0; nf < 4; ++nf) {
                short8 B = *(const short8*)&Wp[(size_t)(rA + nf * 16) * 128 + ks * 32 + kg * 8];
                C[nf] = __builtin_amdgcn_mfma_f32_16x16x32_bf16(B, A, C[nf], 0, 0, 0);
            }
        }
        const int row = base + rA;
        if (row < M) {
            #pragma unroll
            for (int nf = 0; nf < 4; ++nf) {
                const int cb = nf * 16 + kg * 4;
                float4 bv = *(const float4*)&bias[cb];
                float4 o;
                o.x = C[nf][0] + bv.x; o.y = C[nf][1] + bv.y;
                o.z = C[nf][2] + bv.z; o.w = C[nf][3] + bv.w;
                *(float4*)&out[(size_t)row * 64 + cb] = o;
            }
        }
    }
}

// ---------------- column sum for both graphs: out[g*64+c] = sum_n F2[g][n][c] ----------------
__global__ __launch_bounds__(TS)
void colsum2_kernel(const float* __restrict__ Fm, int N, float* __restrict__ out)
{
    __shared__ float red[4][2][64];
    const int t = threadIdx.x;
    const int c = t & 63, rg = t >> 6;
    float s0 = 0.f, s1 = 0.f;
    const int M = 2 * N;
    for (int r = blockIdx.x * 4 + rg; r < M; r += gridDim.x * 4) {
        float v = Fm[(size_t)r * 64 + c];
        if (r < N) s0 += v; else s1 += v;
    }
    red[rg][0][c] = s0; red[rg][1][c] = s1;
    __syncthreads();
    if (rg == 0) {
        atomicAdd(&out[c],      red[0][0][c] + red[1][0][c] + red[2][0][c] + red[3][0][c]);
        atomicAdd(&out[64 + c], red[0][1][c] + red[1][1][c] + red[2][1][c] + red[3][1][c]);
    }
}

extern "C" void kernel_launch(void* const* d_in, const int* in_sizes, int n_in,
                              void* d_out, int out_size, void* d_ws, size_t ws_size,
                              hipStream_t stream)
{
    const int N = in_sizes[0] / F;   // 50000
    const int E = in_sizes[1] / 2;   // 800000
    const int h = E / 2;             // 400000
    const int N2 = 2 * N, h2 = 2 * h;

    // ---- workspace layout (~875 MB) ----
    unsigned short* NTb  = (unsigned short*)d_ws;                    // [2N][400]   80 MB
    unsigned short* P1A = NTb + (size_t)N2 * 400;                    // [2h][100]  160 MB
    unsigned short* P1B = P1A + (size_t)h2 * 100;                    // [2h][100]  160 MB
    unsigned short* P2A = P1B + (size_t)h2 * 100;                    // [2h][100]  160 MB
    unsigned short* P2B = P2A + (size_t)h2 * 100;                    // [2h][100]  160 MB
    unsigned short* xb  = P2B + (size_t)h2 * 100;                    // [2N][128]  25.6 MB
    unsigned short* X1b = xb + (size_t)N2 * 128;                     // [2N][128]
    unsigned short* Ab  = X1b + (size_t)N2 * 128;                    // [2N][128]
    unsigned short* Hb  = Ab + (size_t)N2 * 128;                     // [2N][128]
    float* F2  = (float*)(Hb + (size_t)N2 * 128);                    // [2N][64]   25.6 MB
    int* rp1   = (int*)(F2 + (size_t)N2 * 64);                       // [2][N+1]
    int* rp2   = rp1 + 2 * (N + 1);                                  // [2][N+1]
    int* cnt1  = rp2 + 2 * (N + 1);                                  // [2N]
    int* cnt2  = cnt1 + N2;                                          // [2N]
    int* perm1 = cnt2 + N2;                                          // [2h]
    int* perm2 = perm1 + h2;                                         // [2h]
    int* es1   = perm2 + h2;                                         // [2h]
    int* es2   = es1 + h2;                                           // [2h]
    unsigned short* Wp = (unsigned short*)(es2 + h2);                // [12][112][128]
    unsigned short* Wm = Wp + (size_t)12 * 112 * 128;                // [4][112][128]

    const float* x0g0 = (const float*)d_in[0];
    const int*   ei0  = (const int*)d_in[1];
    const float* ea0  = (const float*)d_in[2];
    const float* x0g1 = (const float*)d_in[3];
    const int*   ei1  = (const int*)d_in[4];
    const float* ea1  = (const float*)d_in[5];
    const float* c1w  = (const float*)d_in[6];
    const float* c1b  = (const float*)d_in[7];
    const float* c1w2 = (const float*)d_in[8];
    const float* c1b2 = (const float*)d_in[9];
    const float* m1w1 = (const float*)d_in[10];
    const float* m1b1 = (const float*)d_in[11];
    const float* m1w2 = (const float*)d_in[12];
    const float* m1b2 = (const float*)d_in[13];
    const float* c2w  = (const float*)d_in[14];
    const float* c2b  = (const float*)d_in[15];
    const float* c2w2 = (const float*)d_in[16];
    const float* c2b2 = (const float*)d_in[17];
    const float* m2w1 = (const float*)d_in[18];
    const float* m2b1 = (const float*)d_in[19];
    const float* m2w2 = (const float*)d_in[20];
    const float* m2b2 = (const float*)d_in[21];

    hipMemsetAsync(d_out, 0, (size_t)out_size * sizeof(float), stream);

    const dim3 blk(TS);
    const size_t SL = (size_t)112 * 128;
    pack_w_kernel<<<(12 * 112 * 128 + TS - 1) / TS, blk, 0, stream>>>(c1w, c1w2, c2w, c2w2, Wp);
    pack_w2_kernel<<<56, blk, 0, stream>>>(m1w1, 100, 100, 100, Wm + 0 * SL);
    pack_w2_kernel<<<56, blk, 0, stream>>>(m1w2, 100, 100, 100, Wm + 1 * SL);
    pack_w2_kernel<<<56, blk, 0, stream>>>(m2w1, 100,  64,  64, Wm + 2 * SL);
    pack_w2_kernel<<<56, blk, 0, stream>>>(m2w2,  64,  64,  64, Wm + 3 * SL);

    // ---- CSR build + packing, both graphs ----
    hipMemsetAsync(cnt1, 0, 2 * (size_t)N2 * sizeof(int), stream);
    hist2_kernel<<<2048, blk, 0, stream>>>(ei0 + E, ei1 + E, h, E, N, cnt1, cnt2);
    scan4_kernel<<<4, 1024, 0, stream>>>(cnt1, cnt2, rp1, rp2, N);
    hipMemsetAsync(cnt1, 0, 2 * (size_t)N2 * sizeof(int), stream);
    scatter2_kernel<<<2048, blk, 0, stream>>>(ei0, ei0 + E, ei1, ei1 + E, h, E, N,
                                              rp1, rp2, cnt1, cnt2, perm1, perm2, es1, es2);
    pack_x2_kernel<<<2048, blk, 0, stream>>>(x0g0, x0g1, N, xb);

    // ---- merged quad edge GEMM: both halves in ONE dispatch (4096 blocks) ----
    gemm_edge_quad<<<4096, blk, 0, stream>>>(ea0, ea1, perm1, perm2, Wp,
                                             P1A, P2A, P1B, P2B, h, 2048);

    const int nblkR = (N2 * 32 + TS - 1) / TS;
    for (int conv = 0; conv < 2; ++conv) {
        const float* cb  = conv ? c2b  : c1b;
        const float* cb2 = conv ? c2b2 : c1b2;
        const unsigned short* xin = conv ? X1b : xb;
        const int iw  = conv ? 2 : 0;
        const int iw2 = conv ? 3 : 1;
        const unsigned short* PA = conv ? P2A : P1A;
        const unsigned short* PB = conv ? P2B : P1B;

        // node transforms: sel0=lo(cw), sel1=hi(cw), sel2=lo(cw2), sel3=hi(cw2)
        gemm_node_mfma<<<2048, blk, 0, stream>>>(xin,
            Wp + (size_t)(4 + iw)  * SL, Wp + (size_t)(8 + iw)  * SL,
            Wp + (size_t)(4 + iw2) * SL, Wp + (size_t)(8 + iw2) * SL,
            NTb, N2);

        // fused reduction over both halves + pack_sum -> Ab (bf16) directly
        seg_reduce_fused<<<nblkR, blk, 0, stream>>>(PA, PB, es1, es2, rp1, rp2,
                                                    cb, cb2, NTb,
                                                    x0g0, x0g1, X1b, Ab,
                                                    N, h, conv);

        if (conv == 0) {
            // X1b = relu(mlp1(Ab))
            gemm_mlp_bf16out<<<2048, blk, 0, stream>>>(Ab, Wm + 0 * SL, m1b1, Hb,  N2, 100);
            gemm_mlp_bf16out<<<2048, blk, 0, stream>>>(Hb, Wm + 1 * SL, m1b2, X1b, N2, 100);
        } else {
            // F2 = mlp2(Ab)
            gemm_mlp_bf16out<<<2048, blk, 0, stream>>>(Ab, Wm + 2 * SL, m2b1, Hb, N2, 64);
            gemm_mlp_f32out<<<2048, blk, 0, stream>>>(Hb, Wm + 3 * SL, m2b2, F2, N2);
        }
    }
    colsum2_kernel<<<512, blk, 0, stream>>>(F2, N, (float*)d_out);
    (void)ws_size; (void)n_in;
}

// Round 12
// 1360.495 us; speedup vs baseline: 1.3130x; 1.0122x over previous
//
#include <hip/hip_runtime.h>

#define F 100
#define TS 256

typedef __attribute__((ext_vector_type(4))) unsigned short us4;
typedef __attribute__((ext_vector_type(8))) short short8;
typedef __attribute__((ext_vector_type(4))) float f32x4;

static __device__ __forceinline__ unsigned short f2bf(float f) {
    unsigned int u = __float_as_uint(f);
    unsigned int r = (u + 0x7FFF + ((u >> 16) & 1)) >> 16;
    return (unsigned short)r;
}
static __device__ __forceinline__ float bf2f(unsigned short u) {
    return __uint_as_float(((unsigned int)u) << 16);
}

// ---------------- CSR build over BOTH graphs ----------------
__global__ __launch_bounds__(TS)
void hist2_kernel(const int* __restrict__ dst0, const int* __restrict__ dst1,
                  int h, int E, int N,
                  int* __restrict__ cnt1, int* __restrict__ cnt2)
{
    for (int idx = blockIdx.x * TS + threadIdx.x; idx < 2 * E; idx += gridDim.x * TS) {
        int g = idx >= E;
        int e = idx - g * E;
        int d = (g ? dst1 : dst0)[e];
        atomicAdd((e < h ? cnt1 : cnt2) + g * N + d, 1);
    }
}

// 4 independent scans in one dispatch: block 0..3 = (half,g)
__global__ __launch_bounds__(1024)
void scan4_kernel(const int* __restrict__ cnt1, const int* __restrict__ cnt2,
                  int* __restrict__ rp1, int* __restrict__ rp2, int n)
{
    const int which = blockIdx.x;
    const int hf = which >> 1, g = which & 1;
    const int* cnt = (hf ? cnt2 : cnt1) + g * n;
    int* rp = (hf ? rp2 : rp1) + g * (n + 1);
    __shared__ int buf[1024];
    __shared__ int carry_s;
    const int t = threadIdx.x;
    if (t == 0) carry_s = 0;
    __syncthreads();
    for (int base = 0; base < n; base += 8192) {
        int v[8], s = 0;
        #pragma unroll
        for (int j = 0; j < 8; ++j) {
            int idx = base + t * 8 + j;
            int x = (idx < n) ? cnt[idx] : 0;
            v[j] = s; s += x;
        }
        buf[t] = s;
        __syncthreads();
        for (int off = 1; off < 1024; off <<= 1) {
            int y = (t >= off) ? buf[t - off] : 0;
            __syncthreads();
            buf[t] += y;
            __syncthreads();
        }
        int excl = carry_s + buf[t] - s;
        #pragma unroll
        for (int j = 0; j < 8; ++j) {
            int idx = base + t * 8 + j;
            if (idx < n) rp[idx] = excl + v[j];
        }
        __syncthreads();
        if (t == 1023) carry_s += buf[1023];
        __syncthreads();
    }
    if (t == 0) rp[n] = carry_s;
}

// scatter both graphs; es stored with +g*N (global node id)
__global__ __launch_bounds__(TS)
void scatter2_kernel(const int* __restrict__ src0, const int* __restrict__ dst0,
                     const int* __restrict__ src1, const int* __restrict__ dst1,
                     int h, int E, int N,
                     const int* __restrict__ rp1, const int* __restrict__ rp2,
                     int* __restrict__ cur1, int* __restrict__ cur2,
                     int* __restrict__ perm1, int* __restrict__ perm2,
                     int* __restrict__ es1, int* __restrict__ es2)
{
    for (int idx = blockIdx.x * TS + threadIdx.x; idx < 2 * E; idx += gridDim.x * TS) {
        int g = idx >= E;
        int e = idx - g * E;
        int d = (g ? dst1 : dst0)[e];
        int s = (g ? src1 : src0)[e];
        if (e < h) {
            int p = rp1[g * (N + 1) + d] + atomicAdd(&cur1[g * N + d], 1);
            perm1[g * h + p] = e; es1[g * h + p] = s + g * N;
        } else {
            int p = rp2[g * (N + 1) + d] + atomicAdd(&cur2[g * N + d], 1);
            perm2[g * h + p] = e; es2[g * h + p] = s + g * N;
        }
    }
}

// ---------------- pack conv W: 12 slices [112][128] bf16, transposed ----------------
__global__ __launch_bounds__(TS)
void pack_w_kernel(const float* w0, const float* w1, const float* w2, const float* w3,
                   unsigned short* __restrict__ Wp)
{
    int i = blockIdx.x * TS + threadIdx.x;
    if (i >= 12 * 112 * 128) return;
    int s = i / (112 * 128);
    int r = i - s * (112 * 128);
    int c = r >> 7, k = r & 127;
    int wi = s & 3, grp = s >> 2;
    const float* w = (wi == 0) ? w0 : (wi == 1) ? w1 : (wi == 2) ? w2 : w3;
    int off = (grp == 0) ? F : ((grp == 1) ? 0 : 2 * F);
    unsigned short v = 0;
    if (c < 100 && k < 100) v = f2bf(w[(off + k) * F + c]);
    Wp[i] = v;
}

__global__ __launch_bounds__(TS)
void pack_w2_kernel(const float* __restrict__ w, int K, int Nc, int ldb,
                    unsigned short* __restrict__ out)
{
    int i = blockIdx.x * TS + threadIdx.x;
    if (i >= 112 * 128) return;
    int c = i >> 7, k = i & 127;
    unsigned short v = 0;
    if (c < Nc && k < K) v = f2bf(w[k * ldb + c]);
    out[i] = v;
}

// ---------------- pack node features (both graphs) fp32 -> bf16, 128-pad ----------------
__global__ __launch_bounds__(TS)
void pack_x2_kernel(const float* __restrict__ x0, const float* __restrict__ x1,
                    int N, unsigned short* __restrict__ xb)
{
    const size_t total = (size_t)N * 2 * 32;
    for (size_t i = (size_t)blockIdx.x * TS + threadIdx.x; i < total; i += (size_t)gridDim.x * TS) {
        int n = (int)(i >> 5), q = (int)(i & 31);
        int g = n >= N;
        const float* x = g ? x1 : x0;
        int nl = n - g * N;
        us4 o = (us4){0, 0, 0, 0};
        if (q < 25) {
            float4 v = *(const float4*)&x[(size_t)nl * 100 + q * 4];
            o.x = f2bf(v.x); o.y = f2bf(v.y); o.z = f2bf(v.z); o.w = f2bf(v.w);
        }
        *(us4*)&xb[((size_t)n << 7) + q * 4] = o;
    }
}

// ---------------- MFMA node transforms; SWAPPED operands -> vectorized us4 stores ----------------
__global__ __launch_bounds__(TS)
void gemm_node_mfma(const unsigned short* __restrict__ xb,
                    const unsigned short* __restrict__ B0, const unsigned short* __restrict__ B1,
                    const unsigned short* __restrict__ B2, const unsigned short* __restrict__ B3,
                    unsigned short* __restrict__ NTb,
                    int M)
{
    const int t = threadIdx.x, lane = t & 63, wv = t >> 6;
    const int rA = lane & 15, kg = lane >> 4;
    const unsigned short* Bp[4] = {B0, B1, B2, B3};
    const int ntiles = (M + 15) >> 4;
    for (int tile = blockIdx.x * 4 + wv; tile < ntiles; tile += gridDim.x * 4) {
        const int base = tile << 4;
        const int arow = min(base + rA, M - 1);
        short8 A[4];
        #pragma unroll
        for (int ks = 0; ks < 4; ++ks)
            A[ks] = *(const short8*)&xb[((size_t)arow << 7) + ks * 32 + kg * 8];
        const int row = base + rA;
        #pragma unroll
        for (int sel = 0; sel < 4; ++sel) {
            const unsigned short* B = Bp[sel];
            f32x4 C[7];
            #pragma unroll
            for (int nf = 0; nf < 7; ++nf) C[nf] = (f32x4){0.f, 0.f, 0.f, 0.f};
            #pragma unroll
            for (int ks = 0; ks < 4; ++ks) {
                #pragma unroll
                for (int nf = 0; nf < 7; ++nf) {
                    short8 Bf = *(const short8*)&B[(size_t)(rA + nf * 16) * 128 + ks * 32 + kg * 8];
                    C[nf] = __builtin_amdgcn_mfma_f32_16x16x32_bf16(Bf, A[ks], C[nf], 0, 0, 0);
                }
            }
            if (row < M) {
                #pragma unroll
                for (int nf = 0; nf < 7; ++nf) {
                    const int cb = nf * 16 + kg * 4;
                    if (cb < 100) {
                        us4 o;
                        o.x = f2bf(C[nf][0]); o.y = f2bf(C[nf][1]);
                        o.z = f2bf(C[nf][2]); o.w = f2bf(C[nf][3]);
                        *(us4*)&NTb[(size_t)row * 400 + sel * 100 + cb] = o;
                    }
                }
            }
        }
    }
}

// ---------------- fused quad edge GEMM, BOTH halves in one dispatch ----------------
// QUAD SCHEDULE IS CLOSED (R3/R6/R9 all regressed): the 188-VGPR dual-C body pins the
// 7 prefetch float4s early; pressure-reducing restructures serialize the gather (R3/R6),
// tight bounds + sched_barrier spill (R9). Inner body is byte-identical to R4/R8.
__global__ __launch_bounds__(TS)
void gemm_edge_quad(const float* __restrict__ ea0, const float* __restrict__ ea1,
                    const int* __restrict__ perm1, const int* __restrict__ perm2,
                    const unsigned short* __restrict__ Wp,   // 12 slices of [112][128]
                    unsigned short* __restrict__ P1A, unsigned short* __restrict__ P2A,
                    unsigned short* __restrict__ P1B, unsigned short* __restrict__ P2B,
                    int h, int HG)
{
    __shared__ unsigned short sA[2][64][136];   // 2 x 17408 B
    const int t = threadIdx.x, lane = t & 63, wv = t >> 6;
    const int rA = lane & 15, kg = lane >> 4;
    const int M = 2 * h;                 // multiple of 64
    const int ngrp = M >> 6;
    const int r_loc = t >> 2, sub = t & 3;

    const int half = blockIdx.x >= HG;
    const int bid = blockIdx.x - (half ? HG : 0);
    const int* perm = half ? perm2 : perm1;
    const unsigned short* W0 = Wp + (size_t)(half ? 1 : 0) * (112 * 128);
    const unsigned short* W1 = Wp + (size_t)(half ? 3 : 2) * (112 * 128);
    unsigned short* P0 = half ? P1B : P1A;
    unsigned short* P1 = half ? P2B : P2A;

    int grp = bid;
    if (grp >= ngrp) return;

    // ---- prologue: stage group 'grp' into buf 0 ----
    {
        const int grow = (grp << 6) + r_loc;
        const int g = grow >= h;
        const int e = perm[grow];
        const float* ea = (g ? ea1 : ea0) + (size_t)e * 100;
        float4 raw[7];
        #pragma unroll
        for (int j = 0; j < 7; ++j) {
            const int q = sub + 4 * j;
            if (q < 25) raw[j] = *(const float4*)&ea[q * 4];
        }
        #pragma unroll
        for (int j = 0; j < 8; ++j) {
            const int q = sub + 4 * j;
            us4 o = (us4){0, 0, 0, 0};
            if (j < 7 && q < 25) {
                o.x = f2bf(raw[j].x); o.y = f2bf(raw[j].y);
                o.z = f2bf(raw[j].z); o.w = f2bf(raw[j].w);
            }
            if (q < 32) *(us4*)&sA[0][r_loc][q * 4] = o;
        }
    }
    __syncthreads();

    int cur = 0;
    while (true) {
        const int nxt = grp + HG;
        const bool more = nxt < ngrp;

        // ---- issue next group's gather loads early (independent, all in flight) ----
        float4 raw[7];
        if (more) {
            const int grow = (nxt << 6) + r_loc;
            const int g = grow >= h;
            const int e = perm[grow];
            const float* ea = (g ? ea1 : ea0) + (size_t)e * 100;
            #pragma unroll
            for (int j = 0; j < 7; ++j) {
                const int q = sub + 4 * j;
                if (q < 25) raw[j] = *(const float4*)&ea[q * 4];
            }
        }

        // ---- compute current group from LDS ----
        {
            const int lrow = wv * 16 + rA;
            short8 A[4];
            #pragma unroll
            for (int ks = 0; ks < 4; ++ks)
                A[ks] = *(const short8*)&sA[cur][lrow][ks * 32 + kg * 8];

            f32x4 C0[7], C1[7];
            #pragma unroll
            for (int nf = 0; nf < 7; ++nf) {
                C0[nf] = (f32x4){0.f, 0.f, 0.f, 0.f};
                C1[nf] = (f32x4){0.f, 0.f, 0.f, 0.f};
            }
            #pragma unroll
            for (int ks = 0; ks < 4; ++ks) {
                #pragma unroll
                for (int nf = 0; nf < 7; ++nf) {
                    short8 B0f = *(const short8*)&W0[(size_t)(rA + nf * 16) * 128 + ks * 32 + kg * 8];
                    C0[nf] = __builtin_amdgcn_mfma_f32_16x16x32_bf16(B0f, A[ks], C0[nf], 0, 0, 0);
                    short8 B1f = *(const short8*)&W1[(size_t)(rA + nf * 16) * 128 + ks * 32 + kg * 8];
                    C1[nf] = __builtin_amdgcn_mfma_f32_16x16x32_bf16(B1f, A[ks], C1[nf], 0, 0, 0);
                }
            }
            const int row = (grp << 6) + lrow;
            #pragma unroll
            for (int nf = 0; nf < 7; ++nf) {
                const int cb = nf * 16 + kg * 4;
                if (cb < 100) {
                    us4 o0, o1;
                    o0.x = f2bf(C0[nf][0]); o0.y = f2bf(C0[nf][1]);
                    o0.z = f2bf(C0[nf][2]); o0.w = f2bf(C0[nf][3]);
                    o1.x = f2bf(C1[nf][0]); o1.y = f2bf(C1[nf][1]);
                    o1.z = f2bf(C1[nf][2]); o1.w = f2bf(C1[nf][3]);
                    *(us4*)&P0[(size_t)row * 100 + cb] = o0;
                    *(us4*)&P1[(size_t)row * 100 + cb] = o1;
                }
            }
        }

        if (!more) break;

        // ---- convert + write staged data into the other buffer ----
        #pragma unroll
        for (int j = 0; j < 8; ++j) {
            const int q = sub + 4 * j;
            us4 o = (us4){0, 0, 0, 0};
            if (j < 7 && q < 25) {
                o.x = f2bf(raw[j].x); o.y = f2bf(raw[j].y);
                o.z = f2bf(raw[j].z); o.w = f2bf(raw[j].w);
            }
            if (q < 32) *(us4*)&sA[cur ^ 1][r_loc][q * 4] = o;
        }
        __syncthreads();
        cur ^= 1; grp = nxt;
    }
}

// ---------------- fused segment reduce + pack_sum, split-edge (2 lanes per node-col) ----------------
// 64 lanes per node: sub (0/1) walks even/odd edges -> serial chain halved, 8 chains
// in flight per lane-pair, and each wave covers exactly ONE node (uniform trip counts).
// Partials combined via __shfl_xor(.,32); sub 0 writes. mode 0: x fp32; mode 1: x bf16 X1b.
__global__ __launch_bounds__(TS)
void seg_reduce_fused(const unsigned short* __restrict__ PA,     // [2h][100] CSR order, half1
                      const unsigned short* __restrict__ PB,     // [2h][100] CSR order, half2
                      const int* __restrict__ es1, const int* __restrict__ es2,
                      const int* __restrict__ rp1, const int* __restrict__ rp2,
                      const float* __restrict__ cb, const float* __restrict__ cb2,
                      const unsigned short* __restrict__ NTb,    // [2N][400]
                      const float* __restrict__ x0, const float* __restrict__ x1,
                      const unsigned short* __restrict__ xbin,
                      unsigned short* __restrict__ Ab,           // [2N][128]
                      int N, int h, int mode)
{
    const int gid = blockIdx.x * TS + threadIdx.x;
    const int n = gid >> 6;
    if (n >= 2 * N) return;
    const int q6 = gid & 63;
    const int sub = q6 >> 5, q = q6 & 31;
    const int c4 = q * 4;
    if (q >= 25) {   // pad columns 100..127
        if (sub == 0) *(us4*)&Ab[((size_t)n << 7) + c4] = (us4){0, 0, 0, 0};
        return;
    }
    const int g = n >= N;
    const int nl = n - g * N;

    // per-half hoisted constants: NT[dst] + bias
    float d1x, d1y, d1z, d1w, d2x, d2y, d2z, d2w;
    {
        const us4 vd1 = *(const us4*)&NTb[(size_t)n * 400 + 0 * 100 + c4];
        const float4 b1 = *(const float4*)&cb[c4];
        d1x = bf2f(vd1.x) + b1.x; d1y = bf2f(vd1.y) + b1.y;
        d1z = bf2f(vd1.z) + b1.z; d1w = bf2f(vd1.w) + b1.w;
        const us4 vd2 = *(const us4*)&NTb[(size_t)n * 400 + 3 * 100 + c4];
        const float4 b2 = *(const float4*)&cb2[c4];
        d2x = bf2f(vd2.x) + b2.x; d2y = bf2f(vd2.y) + b2.y;
        d2z = bf2f(vd2.z) + b2.z; d2w = bf2f(vd2.w) + b2.w;
    }
    const int* rpg1 = rp1 + g * (N + 1);
    const int* rpg2 = rp2 + g * (N + 1);
    int pos1 = max(rpg1[nl], 0) + g * h + sub;
    const int end1 = min(rpg1[nl + 1], h) + g * h;
    int pos2 = max(rpg2[nl], 0) + g * h + sub;
    const int end2 = min(rpg2[nl + 1], h) + g * h;

    float ax = 0.f, ay = 0.f, az = 0.f, aw = 0.f;

    // counts of stride-2 elements for this sub (end - pos >= -1 always)
    const int len1 = (end1 - pos1 + 1) >> 1;
    const int len2 = (end2 - pos2 + 1) >> 1;

    // ---- joint loop: both halves in flight, stride 2 ----
    const int common = min(len1, len2);
    #pragma unroll 2
    for (int i = 0; i < common; ++i) {
        const int i1 = pos1 + 2 * i;
        const int i2 = pos2 + 2 * i;
        const int s1 = es1[i1];
        const int s2 = es2[i2];
        const us4 pv1 = *(const us4*)&PA[(size_t)i1 * 100 + c4];
        const us4 pv2 = *(const us4*)&PB[(size_t)i2 * 100 + c4];
        const us4 v1 = *(const us4*)&NTb[(size_t)s1 * 400 + 1 * 100 + c4];
        const us4 v2 = *(const us4*)&NTb[(size_t)s2 * 400 + 2 * 100 + c4];
        ax += fmaxf(bf2f(pv1.x) + bf2f(v1.x) + d1x, 0.f)
            + fmaxf(bf2f(pv2.x) + bf2f(v2.x) + d2x, 0.f);
        ay += fmaxf(bf2f(pv1.y) + bf2f(v1.y) + d1y, 0.f)
            + fmaxf(bf2f(pv2.y) + bf2f(v2.y) + d2y, 0.f);
        az += fmaxf(bf2f(pv1.z) + bf2f(v1.z) + d1z, 0.f)
            + fmaxf(bf2f(pv2.z) + bf2f(v2.z) + d2z, 0.f);
        aw += fmaxf(bf2f(pv1.w) + bf2f(v1.w) + d1w, 0.f)
            + fmaxf(bf2f(pv2.w) + bf2f(v2.w) + d2w, 0.f);
    }
    pos1 += 2 * common; pos2 += 2 * common;

    // ---- tails (stride 2) ----
    #pragma unroll 2
    for (; pos1 < end1; pos1 += 2) {
        const int s = es1[pos1];
        const us4 pv = *(const us4*)&PA[(size_t)pos1 * 100 + c4];
        const us4 vs = *(const us4*)&NTb[(size_t)s * 400 + 1 * 100 + c4];
        ax += fmaxf(bf2f(pv.x) + bf2f(vs.x) + d1x, 0.f);
        ay += fmaxf(bf2f(pv.y) + bf2f(vs.y) + d1y, 0.f);
        az += fmaxf(bf2f(pv.z) + bf2f(vs.z) + d1z, 0.f);
        aw += fmaxf(bf2f(pv.w) + bf2f(vs.w) + d1w, 0.f);
    }
    #pragma unroll 2
    for (; pos2 < end2; pos2 += 2) {
        const int s = es2[pos2];
        const us4 pv = *(const us4*)&PB[(size_t)pos2 * 100 + c4];
        const us4 vs = *(const us4*)&NTb[(size_t)s * 400 + 2 * 100 + c4];
        ax += fmaxf(bf2f(pv.x) + bf2f(vs.x) + d2x, 0.f);
        ay += fmaxf(bf2f(pv.y) + bf2f(vs.y) + d2y, 0.f);
        az += fmaxf(bf2f(pv.z) + bf2f(vs.z) + d2z, 0.f);
        aw += fmaxf(bf2f(pv.w) + bf2f(vs.w) + d2w, 0.f);
    }

    // ---- combine even/odd partials across the sub split (lanes differ by 32) ----
    ax += __shfl_xor(ax, 32);
    ay += __shfl_xor(ay, 32);
    az += __shfl_xor(az, 32);
    aw += __shfl_xor(aw, 32);
    if (sub != 0) return;

    float4 xv;
    if (mode == 0) {
        const float* x = g ? x1 : x0;
        xv = *(const float4*)&x[(size_t)nl * 100 + c4];
    } else {
        const us4 v = *(const us4*)&xbin[((size_t)n << 7) + c4];
        xv.x = bf2f(v.x); xv.y = bf2f(v.y); xv.z = bf2f(v.z); xv.w = bf2f(v.w);
    }
    us4 o;
    o.x = f2bf(ax + xv.x); o.y = f2bf(ay + xv.y);
    o.z = f2bf(az + xv.z); o.w = f2bf(aw + xv.w);
    *(us4*)&Ab[((size_t)n << 7) + c4] = o;
}

// ---------------- MFMA MLP hop, bf16 out [M][128] (pads zeroed), fused bias + relu ----------------
__global__ __launch_bounds__(TS)
void gemm_mlp_bf16out(const unsigned short* __restrict__ Ab,
                      const unsigned short* __restrict__ Wp,
                      const float* __restrict__ bias,
                      unsigned short* __restrict__ out,
                      int M, int Nc)
{
    const int t = threadIdx.x, lane = t & 63, wv = t >> 6;
    const int rA = lane & 15, kg = lane >> 4;
    const int ntiles = (M + 15) >> 4;
    for (int tile = blockIdx.x * 4 + wv; tile < ntiles; tile += gridDim.x * 4) {
        const int base = tile << 4;
        const int arow = min(base + rA, M - 1);
        f32x4 C[7];
        #pragma unroll
        for (int nf = 0; nf < 7; ++nf) C[nf] = (f32x4){0.f, 0.f, 0.f, 0.f};
        #pragma unroll
        for (int ks = 0; ks < 4; ++ks) {
            short8 A = *(const short8*)&Ab[((size_t)arow << 7) + ks * 32 + kg * 8];
            #pragma unroll
            for (int nf = 0; nf < 7; ++nf) {
                short8 B = *(const short8*)&Wp[(size_t)(rA + nf * 16) * 128 + ks * 32 + kg * 8];
                C[nf] = __builtin_amdgcn_mfma_f32_16x16x32_bf16(B, A, C[nf], 0, 0, 0);
            }
        }
        const int row = base + rA;
        if (row < M) {
            #pragma unroll
            for (int nf = 0; nf < 7; ++nf) {
                const int cb = nf * 16 + kg * 4;
                us4 o = (us4){0, 0, 0, 0};
                if (cb < Nc) {   // Nc multiple of 4
                    float4 bv = *(const float4*)&bias[cb];
                    o.x = f2bf(fmaxf(C[nf][0] + bv.x, 0.f));
                    o.y = f2bf(fmaxf(C[nf][1] + bv.y, 0.f));
                    o.z = f2bf(fmaxf(C[nf][2] + bv.z, 0.f));
                    o.w = f2bf(fmaxf(C[nf][3] + bv.w, 0.f));
                }
                *(us4*)&out[((size_t)row << 7) + cb] = o;
            }
            *(us4*)&out[((size_t)row << 7) + 112 + kg * 4] = (us4){0, 0, 0, 0};
        }
    }
}

// ---------------- MFMA MLP final hop, fp32 out [M][64], bias, no relu ----------------
__global__ __launch_bounds__(TS)
void gemm_mlp_f32out(const unsigned short* __restrict__ Ab,
                     const unsigned short* __restrict__ Wp,
                     const float* __restrict__ bias,
                     float* __restrict__ out,
                     int M)
{
    const int t = threadIdx.x, lane = t & 63, wv = t >> 6;
    const int rA = lane & 15, kg = lane >> 4;
    const int ntiles = (M + 15) >> 4;
    for (int tile = blockIdx.x * 4 + wv; tile < ntiles; tile += gridDim.x * 4) {
        const int base = tile << 4;
        const int arow = min(base + rA, M - 1);
        f32x4 C[4];
        #pragma unroll
        for (int nf = 0; nf < 4; ++nf) C[nf] = (f32x4){0.f, 0.f, 0.f, 0.f};
        #pragma unroll
        for (int ks = 0; ks < 2; ++ks) {
            short8 A = *(const short8*)&Ab[((size_t)arow << 7) + ks * 32 + kg * 8];
            #pragma unroll
            for (int nf = 0; nf < 4; ++nf) {
                short8 B = *(const short8*)&Wp[(size_t)(rA + nf * 16) * 128 + ks * 32 + kg * 8];
                C[nf] = __builtin_amdgcn_mfma_f32_16x16x32_bf16(B, A, C[nf], 0, 0, 0);
            }
        }
        const int row = base + rA;
        if (row < M) {
            #pragma unroll
            for (int nf = 0; nf < 4; ++nf) {
                const int cb = nf * 16 + kg * 4;
                float4 bv = *(const float4*)&bias[cb];
                float4 o;
                o.x = C[nf][0] + bv.x; o.y = C[nf][1] + bv.y;
                o.z = C[nf][2] + bv.z; o.w = C[nf][3] + bv.w;
                *(float4*)&out[(size_t)row * 64 + cb] = o;
            }
        }
    }
}

// ---------------- column sum for both graphs: out[g*64+c] = sum_n F2[g][n][c] ----------------
__global__ __launch_bounds__(TS)
void colsum2_kernel(const float* __restrict__ Fm, int N, float* __restrict__ out)
{
    __shared__ float red[4][2][64];
    const int t = threadIdx.x;
    const int c = t & 63, rg = t >> 6;
    float s0 = 0.f, s1 = 0.f;
    const int M = 2 * N;
    for (int r = blockIdx.x * 4 + rg; r < M; r += gridDim.x * 4) {
        float v = Fm[(size_t)r * 64 + c];
        if (r < N) s0 += v; else s1 += v;
    }
    red[rg][0][c] = s0; red[rg][1][c] = s1;
    __syncthreads();
    if (rg == 0) {
        atomicAdd(&out[c],      red[0][0][c] + red[1][0][c] + red[2][0][c] + red[3][0][c]);
        atomicAdd(&out[64 + c], red[0][1][c] + red[1][1][c] + red[2][1][c] + red[3][1][c]);
    }
}

extern "C" void kernel_launch(void* const* d_in, const int* in_sizes, int n_in,
                              void* d_out, int out_size, void* d_ws, size_t ws_size,
                              hipStream_t stream)
{
    const int N = in_sizes[0] / F;   // 50000
    const int E = in_sizes[1] / 2;   // 800000
    const int h = E / 2;             // 400000
    const int N2 = 2 * N, h2 = 2 * h;

    // ---- workspace layout (~875 MB) ----
    unsigned short* NTb  = (unsigned short*)d_ws;                    // [2N][400]   80 MB
    unsigned short* P1A = NTb + (size_t)N2 * 400;                    // [2h][100]  160 MB
    unsigned short* P1B = P1A + (size_t)h2 * 100;                    // [2h][100]  160 MB
    unsigned short* P2A = P1B + (size_t)h2 * 100;                    // [2h][100]  160 MB
    unsigned short* P2B = P2A + (size_t)h2 * 100;                    // [2h][100]  160 MB
    unsigned short* xb  = P2B + (size_t)h2 * 100;                    // [2N][128]  25.6 MB
    unsigned short* X1b = xb + (size_t)N2 * 128;                     // [2N][128]
    unsigned short* Ab  = X1b + (size_t)N2 * 128;                    // [2N][128]
    unsigned short* Hb  = Ab + (size_t)N2 * 128;                     // [2N][128]
    float* F2  = (float*)(Hb + (size_t)N2 * 128);                    // [2N][64]   25.6 MB
    int* rp1   = (int*)(F2 + (size_t)N2 * 64);                       // [2][N+1]
    int* rp2   = rp1 + 2 * (N + 1);                                  // [2][N+1]
    int* cnt1  = rp2 + 2 * (N + 1);                                  // [2N]
    int* cnt2  = cnt1 + N2;                                          // [2N]
    int* perm1 = cnt2 + N2;                                          // [2h]
    int* perm2 = perm1 + h2;                                         // [2h]
    int* es1   = perm2 + h2;                                         // [2h]
    int* es2   = es1 + h2;                                           // [2h]
    unsigned short* Wp = (unsigned short*)(es2 + h2);                // [12][112][128]
    unsigned short* Wm = Wp + (size_t)12 * 112 * 128;                // [4][112][128]

    const float* x0g0 = (const float*)d_in[0];
    const int*   ei0  = (const int*)d_in[1];
    const float* ea0  = (const float*)d_in[2];
    const float* x0g1 = (const float*)d_in[3];
    const int*   ei1  = (const int*)d_in[4];
    const float* ea1  = (const float*)d_in[5];
    const float* c1w  = (const float*)d_in[6];
    const float* c1b  = (const float*)d_in[7];
    const float* c1w2 = (const float*)d_in[8];
    const float* c1b2 = (const float*)d_in[9];
    const float* m1w1 = (const float*)d_in[10];
    const float* m1b1 = (const float*)d_in[11];
    const float* m1w2 = (const float*)d_in[12];
    const float* m1b2 = (const float*)d_in[13];
    const float* c2w  = (const float*)d_in[14];
    const float* c2b  = (const float*)d_in[15];
    const float* c2w2 = (const float*)d_in[16];
    const float* c2b2 = (const float*)d_in[17];
    const float* m2w1 = (const float*)d_in[18];
    const float* m2b1 = (const float*)d_in[19];
    const float* m2w2 = (const float*)d_in[20];
    const float* m2b2 = (const float*)d_in[21];

    hipMemsetAsync(d_out, 0, (size_t)out_size * sizeof(float), stream);

    const dim3 blk(TS);
    const size_t SL = (size_t)112 * 128;
    pack_w_kernel<<<(12 * 112 * 128 + TS - 1) / TS, blk, 0, stream>>>(c1w, c1w2, c2w, c2w2, Wp);
    pack_w2_kernel<<<56, blk, 0, stream>>>(m1w1, 100, 100, 100, Wm + 0 * SL);
    pack_w2_kernel<<<56, blk, 0, stream>>>(m1w2, 100, 100, 100, Wm + 1 * SL);
    pack_w2_kernel<<<56, blk, 0, stream>>>(m2w1, 100,  64,  64, Wm + 2 * SL);
    pack_w2_kernel<<<56, blk, 0, stream>>>(m2w2,  64,  64,  64, Wm + 3 * SL);

    // ---- CSR build + packing, both graphs ----
    hipMemsetAsync(cnt1, 0, 2 * (size_t)N2 * sizeof(int), stream);
    hist2_kernel<<<2048, blk, 0, stream>>>(ei0 + E, ei1 + E, h, E, N, cnt1, cnt2);
    scan4_kernel<<<4, 1024, 0, stream>>>(cnt1, cnt2, rp1, rp2, N);
    hipMemsetAsync(cnt1, 0, 2 * (size_t)N2 * sizeof(int), stream);
    scatter2_kernel<<<2048, blk, 0, stream>>>(ei0, ei0 + E, ei1, ei1 + E, h, E, N,
                                              rp1, rp2, cnt1, cnt2, perm1, perm2, es1, es2);
    pack_x2_kernel<<<2048, blk, 0, stream>>>(x0g0, x0g1, N, xb);

    // ---- merged quad edge GEMM: both halves in ONE dispatch (4096 blocks) ----
    gemm_edge_quad<<<4096, blk, 0, stream>>>(ea0, ea1, perm1, perm2, Wp,
                                             P1A, P2A, P1B, P2B, h, 2048);

    const int nblkR = (N2 * 64 + TS - 1) / TS;
    for (int conv = 0; conv < 2; ++conv) {
        const float* cb  = conv ? c2b  : c1b;
        const float* cb2 = conv ? c2b2 : c1b2;
        const unsigned short* xin = conv ? X1b : xb;
        const int iw  = conv ? 2 : 0;
        const int iw2 = conv ? 3 : 1;
        const unsigned short* PA = conv ? P2A : P1A;
        const unsigned short* PB = conv ? P2B : P1B;

        // node transforms: sel0=lo(cw), sel1=hi(cw), sel2=lo(cw2), sel3=hi(cw2)
        gemm_node_mfma<<<2048, blk, 0, stream>>>(xin,
            Wp + (size_t)(4 + iw)  * SL, Wp + (size_t)(8 + iw)  * SL,
            Wp + (size_t)(4 + iw2) * SL, Wp + (size_t)(8 + iw2) * SL,
            NTb, N2);

        // fused reduction over both halves + pack_sum -> Ab (bf16) directly
        seg_reduce_fused<<<nblkR, blk, 0, stream>>>(PA, PB, es1, es2, rp1, rp2,
                                                    cb, cb2, NTb,
                                                    x0g0, x0g1, X1b, Ab,
                                                    N, h, conv);

        if (conv == 0) {
            // X1b = relu(mlp1(Ab))
            gemm_mlp_bf16out<<<2048, blk, 0, stream>>>(Ab, Wm + 0 * SL, m1b1, Hb,  N2, 100);
            gemm_mlp_bf16out<<<2048, blk, 0, stream>>>(Hb, Wm + 1 * SL, m1b2, X1b, N2, 100);
        } else {
            // F2 = mlp2(Ab)
            gemm_mlp_bf16out<<<2048, blk, 0, stream>>>(Ab, Wm + 2 * SL, m2b1, Hb, N2, 64);
            gemm_mlp_f32out<<<2048, blk, 0, stream>>>(Hb, Wm + 3 * SL, m2b2, F2, N2);
        }
    }
    colsum2_kernel<<<512, blk, 0, stream>>>(F2, N, (float*)d_out);
    (void)ws_size; (void)n_in;
}

// Round 13
// 1333.942 us; speedup vs baseline: 1.3392x; 1.0199x over previous
//
#include <hip/hip_runtime.h>

#define F 100
#define TS 256

typedef __attribute__((ext_vector_type(4))) unsigned short us4;
typedef __attribute__((ext_vector_type(8))) short short8;
typedef __attribute__((ext_vector_type(4))) float f32x4;

static __device__ __forceinline__ unsigned short f2bf(float f) {
    unsigned int u = __float_as_uint(f);
    unsigned int r = (u + 0x7FFF + ((u >> 16) & 1)) >> 16;
    return (unsigned short)r;
}
static __device__ __forceinline__ float bf2f(unsigned short u) {
    return __uint_as_float(((unsigned int)u) << 16);
}

// ---------------- CSR build over BOTH graphs ----------------
__global__ __launch_bounds__(TS)
void hist2_kernel(const int* __restrict__ dst0, const int* __restrict__ dst1,
                  int h, int E, int N,
                  int* __restrict__ cnt1, int* __restrict__ cnt2)
{
    for (int idx = blockIdx.x * TS + threadIdx.x; idx < 2 * E; idx += gridDim.x * TS) {
        int g = idx >= E;
        int e = idx - g * E;
        int d = (g ? dst1 : dst0)[e];
        atomicAdd((e < h ? cnt1 : cnt2) + g * N + d, 1);
    }
}

// 4 independent scans in one dispatch: block 0..3 = (half,g)
__global__ __launch_bounds__(1024)
void scan4_kernel(const int* __restrict__ cnt1, const int* __restrict__ cnt2,
                  int* __restrict__ rp1, int* __restrict__ rp2, int n)
{
    const int which = blockIdx.x;
    const int hf = which >> 1, g = which & 1;
    const int* cnt = (hf ? cnt2 : cnt1) + g * n;
    int* rp = (hf ? rp2 : rp1) + g * (n + 1);
    __shared__ int buf[1024];
    __shared__ int carry_s;
    const int t = threadIdx.x;
    if (t == 0) carry_s = 0;
    __syncthreads();
    for (int base = 0; base < n; base += 8192) {
        int v[8], s = 0;
        #pragma unroll
        for (int j = 0; j < 8; ++j) {
            int idx = base + t * 8 + j;
            int x = (idx < n) ? cnt[idx] : 0;
            v[j] = s; s += x;
        }
        buf[t] = s;
        __syncthreads();
        for (int off = 1; off < 1024; off <<= 1) {
            int y = (t >= off) ? buf[t - off] : 0;
            __syncthreads();
            buf[t] += y;
            __syncthreads();
        }
        int excl = carry_s + buf[t] - s;
        #pragma unroll
        for (int j = 0; j < 8; ++j) {
            int idx = base + t * 8 + j;
            if (idx < n) rp[idx] = excl + v[j];
        }
        __syncthreads();
        if (t == 1023) carry_s += buf[1023];
        __syncthreads();
    }
    if (t == 0) rp[n] = carry_s;
}

// scatter both graphs; es stored with +g*N (global node id)
__global__ __launch_bounds__(TS)
void scatter2_kernel(const int* __restrict__ src0, const int* __restrict__ dst0,
                     const int* __restrict__ src1, const int* __restrict__ dst1,
                     int h, int E, int N,
                     const int* __restrict__ rp1, const int* __restrict__ rp2,
                     int* __restrict__ cur1, int* __restrict__ cur2,
                     int* __restrict__ perm1, int* __restrict__ perm2,
                     int* __restrict__ es1, int* __restrict__ es2)
{
    for (int idx = blockIdx.x * TS + threadIdx.x; idx < 2 * E; idx += gridDim.x * TS) {
        int g = idx >= E;
        int e = idx - g * E;
        int d = (g ? dst1 : dst0)[e];
        int s = (g ? src1 : src0)[e];
        if (e < h) {
            int p = rp1[g * (N + 1) + d] + atomicAdd(&cur1[g * N + d], 1);
            perm1[g * h + p] = e; es1[g * h + p] = s + g * N;
        } else {
            int p = rp2[g * (N + 1) + d] + atomicAdd(&cur2[g * N + d], 1);
            perm2[g * h + p] = e; es2[g * h + p] = s + g * N;
        }
    }
}

// ---------------- pack conv W: 12 slices [112][128] bf16, transposed ----------------
__global__ __launch_bounds__(TS)
void pack_w_kernel(const float* w0, const float* w1, const float* w2, const float* w3,
                   unsigned short* __restrict__ Wp)
{
    int i = blockIdx.x * TS + threadIdx.x;
    if (i >= 12 * 112 * 128) return;
    int s = i / (112 * 128);
    int r = i - s * (112 * 128);
    int c = r >> 7, k = r & 127;
    int wi = s & 3, grp = s >> 2;
    const float* w = (wi == 0) ? w0 : (wi == 1) ? w1 : (wi == 2) ? w2 : w3;
    int off = (grp == 0) ? F : ((grp == 1) ? 0 : 2 * F);
    unsigned short v = 0;
    if (c < 100 && k < 100) v = f2bf(w[(off + k) * F + c]);
    Wp[i] = v;
}

__global__ __launch_bounds__(TS)
void pack_w2_kernel(const float* __restrict__ w, int K, int Nc, int ldb,
                    unsigned short* __restrict__ out)
{
    int i = blockIdx.x * TS + threadIdx.x;
    if (i >= 112 * 128) return;
    int c = i >> 7, k = i & 127;
    unsigned short v = 0;
    if (c < Nc && k < K) v = f2bf(w[k * ldb + c]);
    out[i] = v;
}

// ---------------- pack node features (both graphs) fp32 -> bf16, 128-pad ----------------
__global__ __launch_bounds__(TS)
void pack_x2_kernel(const float* __restrict__ x0, const float* __restrict__ x1,
                    int N, unsigned short* __restrict__ xb)
{
    const size_t total = (size_t)N * 2 * 32;
    for (size_t i = (size_t)blockIdx.x * TS + threadIdx.x; i < total; i += (size_t)gridDim.x * TS) {
        int n = (int)(i >> 5), q = (int)(i & 31);
        int g = n >= N;
        const float* x = g ? x1 : x0;
        int nl = n - g * N;
        us4 o = (us4){0, 0, 0, 0};
        if (q < 25) {
            float4 v = *(const float4*)&x[(size_t)nl * 100 + q * 4];
            o.x = f2bf(v.x); o.y = f2bf(v.y); o.z = f2bf(v.z); o.w = f2bf(v.w);
        }
        *(us4*)&xb[((size_t)n << 7) + q * 4] = o;
    }
}

// ---------------- MFMA node transforms; SWAPPED operands -> vectorized us4 stores ----------------
__global__ __launch_bounds__(TS)
void gemm_node_mfma(const unsigned short* __restrict__ xb,
                    const unsigned short* __restrict__ B0, const unsigned short* __restrict__ B1,
                    const unsigned short* __restrict__ B2, const unsigned short* __restrict__ B3,
                    unsigned short* __restrict__ NTb,
                    int M)
{
    const int t = threadIdx.x, lane = t & 63, wv = t >> 6;
    const int rA = lane & 15, kg = lane >> 4;
    const unsigned short* Bp[4] = {B0, B1, B2, B3};
    const int ntiles = (M + 15) >> 4;
    for (int tile = blockIdx.x * 4 + wv; tile < ntiles; tile += gridDim.x * 4) {
        const int base = tile << 4;
        const int arow = min(base + rA, M - 1);
        short8 A[4];
        #pragma unroll
        for (int ks = 0; ks < 4; ++ks)
            A[ks] = *(const short8*)&xb[((size_t)arow << 7) + ks * 32 + kg * 8];
        const int row = base + rA;
        #pragma unroll
        for (int sel = 0; sel < 4; ++sel) {
            const unsigned short* B = Bp[sel];
            f32x4 C[7];
            #pragma unroll
            for (int nf = 0; nf < 7; ++nf) C[nf] = (f32x4){0.f, 0.f, 0.f, 0.f};
            #pragma unroll
            for (int ks = 0; ks < 4; ++ks) {
                #pragma unroll
                for (int nf = 0; nf < 7; ++nf) {
                    short8 Bf = *(const short8*)&B[(size_t)(rA + nf * 16) * 128 + ks * 32 + kg * 8];
                    C[nf] = __builtin_amdgcn_mfma_f32_16x16x32_bf16(Bf, A[ks], C[nf], 0, 0, 0);
                }
            }
            if (row < M) {
                #pragma unroll
                for (int nf = 0; nf < 7; ++nf) {
                    const int cb = nf * 16 + kg * 4;
                    if (cb < 100) {
                        us4 o;
                        o.x = f2bf(C[nf][0]); o.y = f2bf(C[nf][1]);
                        o.z = f2bf(C[nf][2]); o.w = f2bf(C[nf][3]);
                        *(us4*)&NTb[(size_t)row * 400 + sel * 100 + cb] = o;
                    }
                }
            }
        }
    }
}

// ---------------- fused quad edge GEMM, BOTH halves in one dispatch ----------------
// QUAD SCHEDULE IS CLOSED (R3/R6/R9 all regressed): the 188-VGPR dual-C body pins the
// 7 prefetch float4s early; pressure-reducing restructures serialize the gather (R3/R6),
// tight bounds + sched_barrier spill (R9). Inner body is byte-identical to R4/R8.
__global__ __launch_bounds__(TS)
void gemm_edge_quad(const float* __restrict__ ea0, const float* __restrict__ ea1,
                    const int* __restrict__ perm1, const int* __restrict__ perm2,
                    const unsigned short* __restrict__ Wp,   // 12 slices of [112][128]
                    unsigned short* __restrict__ P1A, unsigned short* __restrict__ P2A,
                    unsigned short* __restrict__ P1B, unsigned short* __restrict__ P2B,
                    int h, int HG)
{
    __shared__ unsigned short sA[2][64][136];   // 2 x 17408 B
    const int t = threadIdx.x, lane = t & 63, wv = t >> 6;
    const int rA = lane & 15, kg = lane >> 4;
    const int M = 2 * h;                 // multiple of 64
    const int ngrp = M >> 6;
    const int r_loc = t >> 2, sub = t & 3;

    const int half = blockIdx.x >= HG;
    const int bid = blockIdx.x - (half ? HG : 0);
    const int* perm = half ? perm2 : perm1;
    const unsigned short* W0 = Wp + (size_t)(half ? 1 : 0) * (112 * 128);
    const unsigned short* W1 = Wp + (size_t)(half ? 3 : 2) * (112 * 128);
    unsigned short* P0 = half ? P1B : P1A;
    unsigned short* P1 = half ? P2B : P2A;

    int grp = bid;
    if (grp >= ngrp) return;

    // ---- prologue: stage group 'grp' into buf 0 ----
    {
        const int grow = (grp << 6) + r_loc;
        const int g = grow >= h;
        const int e = perm[grow];
        const float* ea = (g ? ea1 : ea0) + (size_t)e * 100;
        float4 raw[7];
        #pragma unroll
        for (int j = 0; j < 7; ++j) {
            const int q = sub + 4 * j;
            if (q < 25) raw[j] = *(const float4*)&ea[q * 4];
        }
        #pragma unroll
        for (int j = 0; j < 8; ++j) {
            const int q = sub + 4 * j;
            us4 o = (us4){0, 0, 0, 0};
            if (j < 7 && q < 25) {
                o.x = f2bf(raw[j].x); o.y = f2bf(raw[j].y);
                o.z = f2bf(raw[j].z); o.w = f2bf(raw[j].w);
            }
            if (q < 32) *(us4*)&sA[0][r_loc][q * 4] = o;
        }
    }
    __syncthreads();

    int cur = 0;
    while (true) {
        const int nxt = grp + HG;
        const bool more = nxt < ngrp;

        // ---- issue next group's gather loads early (independent, all in flight) ----
        float4 raw[7];
        if (more) {
            const int grow = (nxt << 6) + r_loc;
            const int g = grow >= h;
            const int e = perm[grow];
            const float* ea = (g ? ea1 : ea0) + (size_t)e * 100;
            #pragma unroll
            for (int j = 0; j < 7; ++j) {
                const int q = sub + 4 * j;
                if (q < 25) raw[j] = *(const float4*)&ea[q * 4];
            }
        }

        // ---- compute current group from LDS ----
        {
            const int lrow = wv * 16 + rA;
            short8 A[4];
            #pragma unroll
            for (int ks = 0; ks < 4; ++ks)
                A[ks] = *(const short8*)&sA[cur][lrow][ks * 32 + kg * 8];

            f32x4 C0[7], C1[7];
            #pragma unroll
            for (int nf = 0; nf < 7; ++nf) {
                C0[nf] = (f32x4){0.f, 0.f, 0.f, 0.f};
                C1[nf] = (f32x4){0.f, 0.f, 0.f, 0.f};
            }
            #pragma unroll
            for (int ks = 0; ks < 4; ++ks) {
                #pragma unroll
                for (int nf = 0; nf < 7; ++nf) {
                    short8 B0f = *(const short8*)&W0[(size_t)(rA + nf * 16) * 128 + ks * 32 + kg * 8];
                    C0[nf] = __builtin_amdgcn_mfma_f32_16x16x32_bf16(B0f, A[ks], C0[nf], 0, 0, 0);
                    short8 B1f = *(const short8*)&W1[(size_t)(rA + nf * 16) * 128 + ks * 32 + kg * 8];
                    C1[nf] = __builtin_amdgcn_mfma_f32_16x16x32_bf16(B1f, A[ks], C1[nf], 0, 0, 0);
                }
            }
            const int row = (grp << 6) + lrow;
            #pragma unroll
            for (int nf = 0; nf < 7; ++nf) {
                const int cb = nf * 16 + kg * 4;
                if (cb < 100) {
                    us4 o0, o1;
                    o0.x = f2bf(C0[nf][0]); o0.y = f2bf(C0[nf][1]);
                    o0.z = f2bf(C0[nf][2]); o0.w = f2bf(C0[nf][3]);
                    o1.x = f2bf(C1[nf][0]); o1.y = f2bf(C1[nf][1]);
                    o1.z = f2bf(C1[nf][2]); o1.w = f2bf(C1[nf][3]);
                    *(us4*)&P0[(size_t)row * 100 + cb] = o0;
                    *(us4*)&P1[(size_t)row * 100 + cb] = o1;
                }
            }
        }

        if (!more) break;

        // ---- convert + write staged data into the other buffer ----
        #pragma unroll
        for (int j = 0; j < 8; ++j) {
            const int q = sub + 4 * j;
            us4 o = (us4){0, 0, 0, 0};
            if (j < 7 && q < 25) {
                o.x = f2bf(raw[j].x); o.y = f2bf(raw[j].y);
                o.z = f2bf(raw[j].z); o.w = f2bf(raw[j].w);
            }
            if (q < 32) *(us4*)&sA[cur ^ 1][r_loc][q * 4] = o;
        }
        __syncthreads();
        cur ^= 1; grp = nxt;
    }
}

// ---------------- fused segment reduce + pack_sum, split-edge (R12-proven) ----------------
__global__ __launch_bounds__(TS)
void seg_reduce_fused(const unsigned short* __restrict__ PA,     // [2h][100] CSR order, half1
                      const unsigned short* __restrict__ PB,     // [2h][100] CSR order, half2
                      const int* __restrict__ es1, const int* __restrict__ es2,
                      const int* __restrict__ rp1, const int* __restrict__ rp2,
                      const float* __restrict__ cb, const float* __restrict__ cb2,
                      const unsigned short* __restrict__ NTb,    // [2N][400]
                      const float* __restrict__ x0, const float* __restrict__ x1,
                      const unsigned short* __restrict__ xbin,
                      unsigned short* __restrict__ Ab,           // [2N][128]
                      int N, int h, int mode)
{
    const int gid = blockIdx.x * TS + threadIdx.x;
    const int n = gid >> 6;
    if (n >= 2 * N) return;
    const int q6 = gid & 63;
    const int sub = q6 >> 5, q = q6 & 31;
    const int c4 = q * 4;
    if (q >= 25) {   // pad columns 100..127
        if (sub == 0) *(us4*)&Ab[((size_t)n << 7) + c4] = (us4){0, 0, 0, 0};
        return;
    }
    const int g = n >= N;
    const int nl = n - g * N;

    // per-half hoisted constants: NT[dst] + bias
    float d1x, d1y, d1z, d1w, d2x, d2y, d2z, d2w;
    {
        const us4 vd1 = *(const us4*)&NTb[(size_t)n * 400 + 0 * 100 + c4];
        const float4 b1 = *(const float4*)&cb[c4];
        d1x = bf2f(vd1.x) + b1.x; d1y = bf2f(vd1.y) + b1.y;
        d1z = bf2f(vd1.z) + b1.z; d1w = bf2f(vd1.w) + b1.w;
        const us4 vd2 = *(const us4*)&NTb[(size_t)n * 400 + 3 * 100 + c4];
        const float4 b2 = *(const float4*)&cb2[c4];
        d2x = bf2f(vd2.x) + b2.x; d2y = bf2f(vd2.y) + b2.y;
        d2z = bf2f(vd2.z) + b2.z; d2w = bf2f(vd2.w) + b2.w;
    }
    const int* rpg1 = rp1 + g * (N + 1);
    const int* rpg2 = rp2 + g * (N + 1);
    int pos1 = max(rpg1[nl], 0) + g * h + sub;
    const int end1 = min(rpg1[nl + 1], h) + g * h;
    int pos2 = max(rpg2[nl], 0) + g * h + sub;
    const int end2 = min(rpg2[nl + 1], h) + g * h;

    float ax = 0.f, ay = 0.f, az = 0.f, aw = 0.f;

    const int len1 = (end1 - pos1 + 1) >> 1;
    const int len2 = (end2 - pos2 + 1) >> 1;

    // ---- joint loop: both halves in flight, stride 2 ----
    const int common = min(len1, len2);
    #pragma unroll 2
    for (int i = 0; i < common; ++i) {
        const int i1 = pos1 + 2 * i;
        const int i2 = pos2 + 2 * i;
        const int s1 = es1[i1];
        const int s2 = es2[i2];
        const us4 pv1 = *(const us4*)&PA[(size_t)i1 * 100 + c4];
        const us4 pv2 = *(const us4*)&PB[(size_t)i2 * 100 + c4];
        const us4 v1 = *(const us4*)&NTb[(size_t)s1 * 400 + 1 * 100 + c4];
        const us4 v2 = *(const us4*)&NTb[(size_t)s2 * 400 + 2 * 100 + c4];
        ax += fmaxf(bf2f(pv1.x) + bf2f(v1.x) + d1x, 0.f)
            + fmaxf(bf2f(pv2.x) + bf2f(v2.x) + d2x, 0.f);
        ay += fmaxf(bf2f(pv1.y) + bf2f(v1.y) + d1y, 0.f)
            + fmaxf(bf2f(pv2.y) + bf2f(v2.y) + d2y, 0.f);
        az += fmaxf(bf2f(pv1.z) + bf2f(v1.z) + d1z, 0.f)
            + fmaxf(bf2f(pv2.z) + bf2f(v2.z) + d2z, 0.f);
        aw += fmaxf(bf2f(pv1.w) + bf2f(v1.w) + d1w, 0.f)
            + fmaxf(bf2f(pv2.w) + bf2f(v2.w) + d2w, 0.f);
    }
    pos1 += 2 * common; pos2 += 2 * common;

    // ---- tails (stride 2) ----
    #pragma unroll 2
    for (; pos1 < end1; pos1 += 2) {
        const int s = es1[pos1];
        const us4 pv = *(const us4*)&PA[(size_t)pos1 * 100 + c4];
        const us4 vs = *(const us4*)&NTb[(size_t)s * 400 + 1 * 100 + c4];
        ax += fmaxf(bf2f(pv.x) + bf2f(vs.x) + d1x, 0.f);
        ay += fmaxf(bf2f(pv.y) + bf2f(vs.y) + d1y, 0.f);
        az += fmaxf(bf2f(pv.z) + bf2f(vs.z) + d1z, 0.f);
        aw += fmaxf(bf2f(pv.w) + bf2f(vs.w) + d1w, 0.f);
    }
    #pragma unroll 2
    for (; pos2 < end2; pos2 += 2) {
        const int s = es2[pos2];
        const us4 pv = *(const us4*)&PB[(size_t)pos2 * 100 + c4];
        const us4 vs = *(const us4*)&NTb[(size_t)s * 400 + 2 * 100 + c4];
        ax += fmaxf(bf2f(pv.x) + bf2f(vs.x) + d2x, 0.f);
        ay += fmaxf(bf2f(pv.y) + bf2f(vs.y) + d2y, 0.f);
        az += fmaxf(bf2f(pv.z) + bf2f(vs.z) + d2z, 0.f);
        aw += fmaxf(bf2f(pv.w) + bf2f(vs.w) + d2w, 0.f);
    }

    // ---- combine even/odd partials across the sub split (lanes differ by 32) ----
    ax += __shfl_xor(ax, 32);
    ay += __shfl_xor(ay, 32);
    az += __shfl_xor(az, 32);
    aw += __shfl_xor(aw, 32);
    if (sub != 0) return;

    float4 xv;
    if (mode == 0) {
        const float* x = g ? x1 : x0;
        xv = *(const float4*)&x[(size_t)nl * 100 + c4];
    } else {
        const us4 v = *(const us4*)&xbin[((size_t)n << 7) + c4];
        xv.x = bf2f(v.x); xv.y = bf2f(v.y); xv.z = bf2f(v.z); xv.w = bf2f(v.w);
    }
    us4 o;
    o.x = f2bf(ax + xv.x); o.y = f2bf(ay + xv.y);
    o.z = f2bf(az + xv.z); o.w = f2bf(aw + xv.w);
    *(us4*)&Ab[((size_t)n << 7) + c4] = o;
}

// ---------------- FUSED 2-hop MLP (conv0): Ab -> relu(W1+b1) -> LDS -> relu(W2+b2) -> out ----------------
// Each wave owns a full 16-row tile; hop-1 output staged in wave-local LDS (stride 136
// shorts, conflict-free) and consumed by hop-2 in the same wave (no barrier needed).
// M % 16 == 0. Deletes the Hb global round trip.
__global__ __launch_bounds__(TS)
void gemm_mlp2_bf16(const unsigned short* __restrict__ Ab,
                    const unsigned short* __restrict__ W1, const float* __restrict__ b1,
                    const unsigned short* __restrict__ W2, const float* __restrict__ b2,
                    unsigned short* __restrict__ out, int M)
{
    __shared__ unsigned short sH[4][16][136];   // 17408 B
    const int t = threadIdx.x, lane = t & 63, wv = t >> 6;
    const int rA = lane & 15, kg = lane >> 4;
    const int ntiles = M >> 4;
    for (int tile = blockIdx.x * 4 + wv; tile < ntiles; tile += gridDim.x * 4) {
        const int row = (tile << 4) + rA;
        // ---- hop 1 ----
        f32x4 C[7];
        #pragma unroll
        for (int nf = 0; nf < 7; ++nf) C[nf] = (f32x4){0.f, 0.f, 0.f, 0.f};
        #pragma unroll
        for (int ks = 0; ks < 4; ++ks) {
            short8 A = *(const short8*)&Ab[((size_t)row << 7) + ks * 32 + kg * 8];
            #pragma unroll
            for (int nf = 0; nf < 7; ++nf) {
                short8 B = *(const short8*)&W1[(size_t)(rA + nf * 16) * 128 + ks * 32 + kg * 8];
                C[nf] = __builtin_amdgcn_mfma_f32_16x16x32_bf16(B, A, C[nf], 0, 0, 0);
            }
        }
        #pragma unroll
        for (int nf = 0; nf < 7; ++nf) {
            const int cbp = nf * 16 + kg * 4;
            us4 o = (us4){0, 0, 0, 0};
            if (cbp < 100) {
                float4 bv = *(const float4*)&b1[cbp];
                o.x = f2bf(fmaxf(C[nf][0] + bv.x, 0.f));
                o.y = f2bf(fmaxf(C[nf][1] + bv.y, 0.f));
                o.z = f2bf(fmaxf(C[nf][2] + bv.z, 0.f));
                o.w = f2bf(fmaxf(C[nf][3] + bv.w, 0.f));
            }
            *(us4*)&sH[wv][rA][cbp] = o;
        }
        *(us4*)&sH[wv][rA][112 + kg * 4] = (us4){0, 0, 0, 0};
        // ---- hop 2 (same wave; compiler-inserted lgkmcnt covers the LDS RAW) ----
        f32x4 D[7];
        #pragma unroll
        for (int nf = 0; nf < 7; ++nf) D[nf] = (f32x4){0.f, 0.f, 0.f, 0.f};
        #pragma unroll
        for (int ks = 0; ks < 4; ++ks) {
            short8 A2 = *(const short8*)&sH[wv][rA][ks * 32 + kg * 8];
            #pragma unroll
            for (int nf = 0; nf < 7; ++nf) {
                short8 B = *(const short8*)&W2[(size_t)(rA + nf * 16) * 128 + ks * 32 + kg * 8];
                D[nf] = __builtin_amdgcn_mfma_f32_16x16x32_bf16(B, A2, D[nf], 0, 0, 0);
            }
        }
        #pragma unroll
        for (int nf = 0; nf < 7; ++nf) {
            const int cbp = nf * 16 + kg * 4;
            us4 o = (us4){0, 0, 0, 0};
            if (cbp < 100) {
                float4 bv = *(const float4*)&b2[cbp];
                o.x = f2bf(fmaxf(D[nf][0] + bv.x, 0.f));
                o.y = f2bf(fmaxf(D[nf][1] + bv.y, 0.f));
                o.z = f2bf(fmaxf(D[nf][2] + bv.z, 0.f));
                o.w = f2bf(fmaxf(D[nf][3] + bv.w, 0.f));
            }
            *(us4*)&out[((size_t)row << 7) + cbp] = o;
        }
        *(us4*)&out[((size_t)row << 7) + 112 + kg * 4] = (us4){0, 0, 0, 0};
    }
}

// ---------------- FUSED 2-hop MLP + colsum (conv1): Ab -> relu(100->64) -> LDS ->
// (64->64)+bias -> per-graph column sums -> d_out atomics. F2 never materialized.
// N % 16 == 0 so each tile lies entirely in one graph.
__global__ __launch_bounds__(TS)
void gemm_mlp2_colsum(const unsigned short* __restrict__ Ab,
                      const unsigned short* __restrict__ W1, const float* __restrict__ b1,
                      const unsigned short* __restrict__ W2, const float* __restrict__ b2,
                      float* __restrict__ outp, int M, int N)
{
    __shared__ unsigned short sH[4][16][136];   // 17408 B
    __shared__ float sums[128];
    const int t = threadIdx.x, lane = t & 63, wv = t >> 6;
    const int rA = lane & 15, kg = lane >> 4;
    if (t < 128) sums[t] = 0.f;
    __syncthreads();

    f32x4 acc0[4], acc1[4];
    #pragma unroll
    for (int nf = 0; nf < 4; ++nf) {
        acc0[nf] = (f32x4){0.f, 0.f, 0.f, 0.f};
        acc1[nf] = (f32x4){0.f, 0.f, 0.f, 0.f};
    }

    const int ntiles = M >> 4;
    for (int tile = blockIdx.x * 4 + wv; tile < ntiles; tile += gridDim.x * 4) {
        const int base = tile << 4;
        const int row = base + rA;
        // ---- hop 1: 100 -> 64, relu ----
        f32x4 C[4];
        #pragma unroll
        for (int nf = 0; nf < 4; ++nf) C[nf] = (f32x4){0.f, 0.f, 0.f, 0.f};
        #pragma unroll
        for (int ks = 0; ks < 4; ++ks) {
            short8 A = *(const short8*)&Ab[((size_t)row << 7) + ks * 32 + kg * 8];
            #pragma unroll
            for (int nf = 0; nf < 4; ++nf) {
                short8 B = *(const short8*)&W1[(size_t)(rA + nf * 16) * 128 + ks * 32 + kg * 8];
                C[nf] = __builtin_amdgcn_mfma_f32_16x16x32_bf16(B, A, C[nf], 0, 0, 0);
            }
        }
        #pragma unroll
        for (int nf = 0; nf < 4; ++nf) {
            const int cbp = nf * 16 + kg * 4;     // < 64
            float4 bv = *(const float4*)&b1[cbp];
            us4 o;
            o.x = f2bf(fmaxf(C[nf][0] + bv.x, 0.f));
            o.y = f2bf(fmaxf(C[nf][1] + bv.y, 0.f));
            o.z = f2bf(fmaxf(C[nf][2] + bv.z, 0.f));
            o.w = f2bf(fmaxf(C[nf][3] + bv.w, 0.f));
            *(us4*)&sH[wv][rA][cbp] = o;
        }
        // ---- hop 2: 64 -> 64, +bias, no relu; accumulate column sums ----
        f32x4 D[4];
        #pragma unroll
        for (int nf = 0; nf < 4; ++nf) D[nf] = (f32x4){0.f, 0.f, 0.f, 0.f};
        #pragma unroll
        for (int ks = 0; ks < 2; ++ks) {
            short8 A2 = *(const short8*)&sH[wv][rA][ks * 32 + kg * 8];
            #pragma unroll
            for (int nf = 0; nf < 4; ++nf) {
                short8 B = *(const short8*)&W2[(size_t)(rA + nf * 16) * 128 + ks * 32 + kg * 8];
                D[nf] = __builtin_amdgcn_mfma_f32_16x16x32_bf16(B, A2, D[nf], 0, 0, 0);
            }
        }
        if (base >= N) {
            #pragma unroll
            for (int nf = 0; nf < 4; ++nf) {
                float4 bv = *(const float4*)&b2[nf * 16 + kg * 4];
                acc1[nf][0] += D[nf][0] + bv.x; acc1[nf][1] += D[nf][1] + bv.y;
                acc1[nf][2] += D[nf][2] + bv.z; acc1[nf][3] += D[nf][3] + bv.w;
            }
        } else {
            #pragma unroll
            for (int nf = 0; nf < 4; ++nf) {
                float4 bv = *(const float4*)&b2[nf * 16 + kg * 4];
                acc0[nf][0] += D[nf][0] + bv.x; acc0[nf][1] += D[nf][1] + bv.y;
                acc0[nf][2] += D[nf][2] + bv.z; acc0[nf][3] += D[nf][3] + bv.w;
            }
        }
    }

    // ---- reduce across the 16 rA lanes (xor 1,2,4,8 within each kg group) ----
    #pragma unroll
    for (int nf = 0; nf < 4; ++nf) {
        #pragma unroll
        for (int r = 0; r < 4; ++r) {
            float v0 = acc0[nf][r], v1 = acc1[nf][r];
            v0 += __shfl_xor(v0, 1); v0 += __shfl_xor(v0, 2);
            v0 += __shfl_xor(v0, 4); v0 += __shfl_xor(v0, 8);
            v1 += __shfl_xor(v1, 1); v1 += __shfl_xor(v1, 2);
            v1 += __shfl_xor(v1, 4); v1 += __shfl_xor(v1, 8);
            if (rA == 0) {
                const int f = nf * 16 + kg * 4 + r;
                atomicAdd(&sums[f], v0);
                atomicAdd(&sums[64 + f], v1);
            }
        }
    }
    __syncthreads();
    if (t < 128) atomicAdd(&outp[t], sums[t]);
}

extern "C" void kernel_launch(void* const* d_in, const int* in_sizes, int n_in,
                              void* d_out, int out_size, void* d_ws, size_t ws_size,
                              hipStream_t stream)
{
    const int N = in_sizes[0] / F;   // 50000
    const int E = in_sizes[1] / 2;   // 800000
    const int h = E / 2;             // 400000
    const int N2 = 2 * N, h2 = 2 * h;

    // ---- workspace layout (~875 MB) ----
    unsigned short* NTb  = (unsigned short*)d_ws;                    // [2N][400]   80 MB
    unsigned short* P1A = NTb + (size_t)N2 * 400;                    // [2h][100]  160 MB
    unsigned short* P1B = P1A + (size_t)h2 * 100;                    // [2h][100]  160 MB
    unsigned short* P2A = P1B + (size_t)h2 * 100;                    // [2h][100]  160 MB
    unsigned short* P2B = P2A + (size_t)h2 * 100;                    // [2h][100]  160 MB
    unsigned short* xb  = P2B + (size_t)h2 * 100;                    // [2N][128]  25.6 MB
    unsigned short* X1b = xb + (size_t)N2 * 128;                     // [2N][128]
    unsigned short* Ab  = X1b + (size_t)N2 * 128;                    // [2N][128]
    unsigned short* Hb  = Ab + (size_t)N2 * 128;                     // [2N][128] (unused)
    float* F2  = (float*)(Hb + (size_t)N2 * 128);                    // [2N][64] (unused)
    int* rp1   = (int*)(F2 + (size_t)N2 * 64);                       // [2][N+1]
    int* rp2   = rp1 + 2 * (N + 1);                                  // [2][N+1]
    int* cnt1  = rp2 + 2 * (N + 1);                                  // [2N]
    int* cnt2  = cnt1 + N2;                                          // [2N]
    int* perm1 = cnt2 + N2;                                          // [2h]
    int* perm2 = perm1 + h2;                                         // [2h]
    int* es1   = perm2 + h2;                                         // [2h]
    int* es2   = es1 + h2;                                           // [2h]
    unsigned short* Wp = (unsigned short*)(es2 + h2);                // [12][112][128]
    unsigned short* Wm = Wp + (size_t)12 * 112 * 128;                // [4][112][128]

    const float* x0g0 = (const float*)d_in[0];
    const int*   ei0  = (const int*)d_in[1];
    const float* ea0  = (const float*)d_in[2];
    const float* x0g1 = (const float*)d_in[3];
    const int*   ei1  = (const int*)d_in[4];
    const float* ea1  = (const float*)d_in[5];
    const float* c1w  = (const float*)d_in[6];
    const float* c1b  = (const float*)d_in[7];
    const float* c1w2 = (const float*)d_in[8];
    const float* c1b2 = (const float*)d_in[9];
    const float* m1w1 = (const float*)d_in[10];
    const float* m1b1 = (const float*)d_in[11];
    const float* m1w2 = (const float*)d_in[12];
    const float* m1b2 = (const float*)d_in[13];
    const float* c2w  = (const float*)d_in[14];
    const float* c2b  = (const float*)d_in[15];
    const float* c2w2 = (const float*)d_in[16];
    const float* c2b2 = (const float*)d_in[17];
    const float* m2w1 = (const float*)d_in[18];
    const float* m2b1 = (const float*)d_in[19];
    const float* m2w2 = (const float*)d_in[20];
    const float* m2b2 = (const float*)d_in[21];

    hipMemsetAsync(d_out, 0, (size_t)out_size * sizeof(float), stream);

    const dim3 blk(TS);
    const size_t SL = (size_t)112 * 128;
    pack_w_kernel<<<(12 * 112 * 128 + TS - 1) / TS, blk, 0, stream>>>(c1w, c1w2, c2w, c2w2, Wp);
    pack_w2_kernel<<<56, blk, 0, stream>>>(m1w1, 100, 100, 100, Wm + 0 * SL);
    pack_w2_kernel<<<56, blk, 0, stream>>>(m1w2, 100, 100, 100, Wm + 1 * SL);
    pack_w2_kernel<<<56, blk, 0, stream>>>(m2w1, 100,  64,  64, Wm + 2 * SL);
    pack_w2_kernel<<<56, blk, 0, stream>>>(m2w2,  64,  64,  64, Wm + 3 * SL);

    // ---- CSR build + packing, both graphs ----
    hipMemsetAsync(cnt1, 0, 2 * (size_t)N2 * sizeof(int), stream);
    hist2_kernel<<<2048, blk, 0, stream>>>(ei0 + E, ei1 + E, h, E, N, cnt1, cnt2);
    scan4_kernel<<<4, 1024, 0, stream>>>(cnt1, cnt2, rp1, rp2, N);
    hipMemsetAsync(cnt1, 0, 2 * (size_t)N2 * sizeof(int), stream);
    scatter2_kernel<<<2048, blk, 0, stream>>>(ei0, ei0 + E, ei1, ei1 + E, h, E, N,
                                              rp1, rp2, cnt1, cnt2, perm1, perm2, es1, es2);
    pack_x2_kernel<<<2048, blk, 0, stream>>>(x0g0, x0g1, N, xb);

    // ---- merged quad edge GEMM: both halves in ONE dispatch (4096 blocks) ----
    gemm_edge_quad<<<4096, blk, 0, stream>>>(ea0, ea1, perm1, perm2, Wp,
                                             P1A, P2A, P1B, P2B, h, 2048);

    const int nblkR = (N2 * 64 + TS - 1) / TS;
    const int nblkM = (N2 / 16 + 3) / 4;   // fused MLP: 1 tile per wave slot
    for (int conv = 0; conv < 2; ++conv) {
        const float* cb  = conv ? c2b  : c1b;
        const float* cb2 = conv ? c2b2 : c1b2;
        const unsigned short* xin = conv ? X1b : xb;
        const int iw  = conv ? 2 : 0;
        const int iw2 = conv ? 3 : 1;
        const unsigned short* PA = conv ? P2A : P1A;
        const unsigned short* PB = conv ? P2B : P1B;

        // node transforms: sel0=lo(cw), sel1=hi(cw), sel2=lo(cw2), sel3=hi(cw2)
        gemm_node_mfma<<<2048, blk, 0, stream>>>(xin,
            Wp + (size_t)(4 + iw)  * SL, Wp + (size_t)(8 + iw)  * SL,
            Wp + (size_t)(4 + iw2) * SL, Wp + (size_t)(8 + iw2) * SL,
            NTb, N2);

        // fused reduction over both halves + pack_sum -> Ab (bf16) directly
        seg_reduce_fused<<<nblkR, blk, 0, stream>>>(PA, PB, es1, es2, rp1, rp2,
                                                    cb, cb2, NTb,
                                                    x0g0, x0g1, X1b, Ab,
                                                    N, h, conv);

        if (conv == 0) {
            // X1b = relu(mlp1(Ab)) — both hops fused, LDS intermediate
            gemm_mlp2_bf16<<<nblkM, blk, 0, stream>>>(Ab, Wm + 0 * SL, m1b1,
                                                      Wm + 1 * SL, m1b2, X1b, N2);
        } else {
            // d_out += colsum(mlp2(Ab)) — both hops + colsum fused
            gemm_mlp2_colsum<<<nblkM, blk, 0, stream>>>(Ab, Wm + 2 * SL, m2b1,
                                                        Wm + 3 * SL, m2b2,
                                                        (float*)d_out, N2, N);
        }
    }
    (void)ws_size; (void)n_in;
}